// Round 20
// baseline (638.477 us; speedup 1.0000x reference)
//
#include <hip/hip_runtime.h>
#include <hip/hip_bf16.h>
#include <cstdint>

#define NN 50000
#define EE 800000
#define RR 8
#define GG 128
#define D0 384
#define DL 256
#define NCR 50       // total embedding rows: 33+5+3+4+2+3

typedef __attribute__((ext_vector_type(8))) short bf16x8;
typedef __attribute__((ext_vector_type(4))) float f32x4;

__device__ __forceinline__ float sigmoidf_(float x) { return 1.0f / (1.0f + expf(-x)); }

__device__ __forceinline__ ushort f2bf(float f) {
    uint u = __float_as_uint(f);
    u += 0x7fffu + ((u >> 16) & 1u);
    return (ushort)(u >> 16);
}
__device__ __forceinline__ uint pack2bf(float lo, float hi) {
    return (uint)f2bf(lo) | ((uint)f2bf(hi) << 16);
}
__device__ __forceinline__ float bf2f(ushort u) {
    return __uint_as_float((uint)u << 16);
}

// acc[0..7] += w * bf16x8(v)
__device__ __forceinline__ void accw8(float* s, uint4 a, float w) {
    s[0] += w * __uint_as_float(a.x << 16);
    s[1] += w * __uint_as_float(a.x & 0xffff0000u);
    s[2] += w * __uint_as_float(a.y << 16);
    s[3] += w * __uint_as_float(a.y & 0xffff0000u);
    s[4] += w * __uint_as_float(a.z << 16);
    s[5] += w * __uint_as_float(a.z & 0xffff0000u);
    s[6] += w * __uint_as_float(a.w << 16);
    s[7] += w * __uint_as_float(a.w & 0xffff0000u);
}

// unpack 8 bf16 to fp32
__device__ __forceinline__ void unp8(float* f, uint4 a) {
    f[0] = __uint_as_float(a.x << 16);
    f[1] = __uint_as_float(a.x & 0xffff0000u);
    f[2] = __uint_as_float(a.y << 16);
    f[3] = __uint_as_float(a.y & 0xffff0000u);
    f[4] = __uint_as_float(a.z << 16);
    f[5] = __uint_as_float(a.z & 0xffff0000u);
    f[6] = __uint_as_float(a.w << 16);
    f[7] = __uint_as_float(a.w & 0xffff0000u);
}
__device__ __forceinline__ uint4 pack8bf(const float* f) {
    uint4 p;
    p.x = pack2bf(f[0], f[1]);
    p.y = pack2bf(f[2], f[3]);
    p.z = pack2bf(f[4], f[5]);
    p.w = pack2bf(f[6], f[7]);
    return p;
}

// order-preserving float->uint encoding for atomicMax
__device__ __forceinline__ unsigned fenc(float x) {
    unsigned u = __float_as_uint(x);
    return (u & 0x80000000u) ? ~u : (u | 0x80000000u);
}
__device__ __forceinline__ float fdec(unsigned u) {
    unsigned b = (u & 0x80000000u) ? (u & 0x7fffffffu) : ~u;
    return __uint_as_float(b);
}

// ---------------- layer-1 LUT build: T[cr][r][col] = emb_row(cr) @ W1[r, slice] ----
__global__ __launch_bounds__(256) void lutbuild_kernel(
    const float* __restrict__ e0, const float* __restrict__ e1,
    const float* __restrict__ e2, const float* __restrict__ e3,
    const float* __restrict__ e4, const float* __restrict__ e5,
    const float* __restrict__ W1, const float* __restrict__ root1,
    ushort* __restrict__ T)          // [50][9][256] bf16
{
    int b = blockIdx.x;              // 0..449
    int cr = b / 9;
    int r  = b - cr * 9;
    int t, c;
    if      (cr < 33) { t = 0; c = cr; }
    else if (cr < 38) { t = 1; c = cr - 33; }
    else if (cr < 41) { t = 2; c = cr - 38; }
    else if (cr < 45) { t = 3; c = cr - 41; }
    else if (cr < 47) { t = 4; c = cr - 45; }
    else              { t = 5; c = cr - 47; }
    const float* emb;
    switch (t) {
        case 0: emb = e0; break; case 1: emb = e1; break; case 2: emb = e2; break;
        case 3: emb = e3; break; case 4: emb = e4; break; default: emb = e5; break;
    }
    const float* er = emb + c * 64;
    int col = threadIdx.x;           // 256
    const float* Wb = (r < 8) ? (W1 + ((size_t)r * D0 + t * 64) * DL + col)
                              : (root1 + (size_t)(t * 64) * DL + col);
    float s = 0.f;
    #pragma unroll 8
    for (int k = 0; k < 64; k++) s += er[k] * Wb[(size_t)k * DL];
    T[(size_t)(cr * 9 + r) * DL + col] = f2bf(s);
}

// ---------------- layer-1 DIRECT-LUT gather (fuses lutsum + gather) ----------------
// Per edge: decode (src, r) from epk (src*8+r), read x[src] (L2-resident),
// accumulate w * sum_t T[x[src,t]][r] straight from the LDS LUT slice.
// Tiling: blockIdx.y = col quarter (64 cols); two launches cover relation
// halves [r0, r0+4). LDS = 4 rels x 50 rows x 72-stride bf16 = 28.8 KB
// (stride 72 = 144B: 16B-aligned, rotates 4 banks/row -> ~conflict-free).
// Eliminates hrc materialization for layer 1 entirely.
__global__ __launch_bounds__(256) void gather_lut(
    const ushort* __restrict__ T,    // [50][9][256] bf16
    const int* __restrict__ x,       // [N][6]
    const int2* __restrict__ epk,    // (src*8+r, weight)
    const int* __restrict__ offs,    // [N*8]
    ushort* __restrict__ hacc,       // [N][256] bf16
    int r0, int first)
{
    constexpr int STR = 72;
    __shared__ ushort Ts[4 * NCR * STR];   // 28.8 KB
    const int q = blockIdx.y;              // col quarter 0..3
    int t = threadIdx.x;
    for (int i = t; i < 4 * NCR * 8; i += 256) {
        int row = i >> 3, j = i & 7;       // row = r*NCR + cr
        int r = row / NCR, cr = row - r * NCR;
        uint4 v = *(const uint4*)&T[(size_t)(cr * 9 + r0 + r) * 256 + q * 64 + j * 8];
        *(uint4*)&Ts[row * STR + j * 8] = v;
    }
    __syncthreads();

    const int slot = t >> 3;          // node slot 0..31
    const int l    = t & 7;
    const int c    = l * 8;           // col within quarter

    int n = blockIdx.x * 32 + slot;
    if (n >= NN) return;
    int e    = offs[n * 8 + r0];
    int endE = (r0 + 4 == 8) ? ((n == NN - 1) ? EE : offs[n * 8 + 8])
                             : offs[n * 8 + r0 + 4];

    float acc[8];
    if (first) {
        #pragma unroll
        for (int qq = 0; qq < 8; qq++) acc[qq] = 0.f;
    } else {
        uint4 a = *(const uint4*)&hacc[(size_t)n * DL + q * 64 + c];
        unp8(acc, a);
    }

    const int cumc[6] = {0, 33, 38, 41, 45, 47};
    for (; e < endE; e += 2) {
        int e1 = min(e + 1, endE - 1);
        int2 p0 = epk[e], p1 = epk[e1];
        float w0 = __int_as_float(p0.y);
        float w1 = (e + 1 < endE) ? __int_as_float(p1.y) : 0.f;
        int s0 = p0.x >> 3, ra = (p0.x & 7) - r0;
        int s1 = p1.x >> 3, rb = (p1.x & 7) - r0;
        const int* xp0 = x + s0 * 6;
        const int* xp1 = x + s1 * 6;
        int cra[6], crb[6];
        #pragma unroll
        for (int tb = 0; tb < 6; tb++) { cra[tb] = cumc[tb] + xp0[tb]; }
        #pragma unroll
        for (int tb = 0; tb < 6; tb++) { crb[tb] = cumc[tb] + xp1[tb]; }
        #pragma unroll
        for (int tb = 0; tb < 6; tb++) {
            uint4 v = *(const uint4*)&Ts[(ra * NCR + cra[tb]) * STR + c];
            accw8(acc, v, w0);
        }
        #pragma unroll
        for (int tb = 0; tb < 6; tb++) {
            uint4 v = *(const uint4*)&Ts[(rb * NCR + crb[tb]) * STR + c];
            accw8(acc, v, w1);
        }
    }

    *(uint4*)&hacc[(size_t)n * DL + q * 64 + c] = pack8bf(acc);
}

// ---------------- layer-1 finalize: h1 = sigmoid(LUT_root + hacc + b1) ----------------
__global__ __launch_bounds__(256) void lutfin_kernel(
    const ushort* __restrict__ T, const int* __restrict__ x,
    const ushort* __restrict__ hacc, const float* __restrict__ b1,
    ushort* __restrict__ h1)
{
    __shared__ ushort Ts[NCR * 256];  // root slice (r=8), 25.6 KB
    int t = threadIdx.x;
    for (int i = t; i < NCR * 256; i += 256) {
        int cr = i >> 8, col = i & 255;
        Ts[i] = T[(size_t)(cr * 9 + 8) * 256 + col];
    }
    __syncthreads();

    const int slot = t >> 5;          // 8 nodes per block-iteration
    const int l = t & 31;
    const int c = l * 8;

    for (int base = blockIdx.x * 8; base < NN; base += gridDim.x * 8) {
        int n = base + slot;
        if (n < NN) {
            const int* xp = x + n * 6;
            const int cumc[6] = {0, 33, 38, 41, 45, 47};
            float acc[8];
            float4 b0 = *(const float4*)&b1[c];
            float4 bb = *(const float4*)&b1[c + 4];
            acc[0] = b0.x; acc[1] = b0.y; acc[2] = b0.z; acc[3] = b0.w;
            acc[4] = bb.x; acc[5] = bb.y; acc[6] = bb.z; acc[7] = bb.w;
            #pragma unroll
            for (int tb = 0; tb < 6; tb++) {
                int cr = cumc[tb] + xp[tb];
                uint4 v = *(const uint4*)&Ts[cr * 256 + c];
                accw8(acc, v, 1.0f);
            }
            uint4 hv = *(const uint4*)&hacc[(size_t)n * DL + c];
            float hf[8]; unp8(hf, hv);
            #pragma unroll
            for (int q = 0; q < 8; q++) acc[q] = sigmoidf_(acc[q] + hf[q]);
            *(uint4*)&h1[(size_t)n * DL + c] = pack8bf(acc);
        }
    }
}

// ---------------- weight convert + transpose: WbT[r*256+n][k] = bf16(W[r][k][n]) ----------------
__global__ __launch_bounds__(256) void cvtT_kernel(
    const float* __restrict__ W, const float* __restrict__ root,
    ushort* __restrict__ WbT, int nrel, int IN)
{
    int idx = blockIdx.x * 256 + threadIdx.x;
    int tot = (nrel + 1) * DL * IN;
    if (idx >= tot) return;
    int k = idx % IN;
    int rn = idx / IN;
    int n = rn % DL;
    int r = rn / DL;
    float v = (r < nrel) ? W[((size_t)r * IN + k) * DL + n] : root[(size_t)k * DL + n];
    WbT[idx] = f2bf(v);
}

// ---------------- CSR build ----------------
__global__ __launch_bounds__(256) void count_kernel(
    const int* __restrict__ dst, const int* __restrict__ et, int* __restrict__ counts)
{
    int i = blockIdx.x * 256 + threadIdx.x;
    if (i < EE) atomicAdd(&counts[dst[i] * RR + et[i]], 1);
}

#define SCAN_CHUNK 4096
__global__ __launch_bounds__(256) void scanA_kernel(const int* __restrict__ cnt, int M, int* __restrict__ blkSums)
{
    __shared__ int s[256];
    int b = blockIdx.x, t = threadIdx.x;
    int base = b * SCAN_CHUNK + t * 16;
    int tot = 0;
    #pragma unroll
    for (int i = 0; i < 16; i++) { int idx = base + i; if (idx < M) tot += cnt[idx]; }
    s[t] = tot; __syncthreads();
    for (int off = 128; off > 0; off >>= 1) {
        if (t < off) s[t] += s[t + off];
        __syncthreads();
    }
    if (t == 0) blkSums[b] = s[0];
}

// wave-parallel exclusive scan over NB<=128 block sums
__global__ void scanB_kernel(const int* __restrict__ blkSums, int NB, int* __restrict__ blkOff)
{
    int l = threadIdx.x;              // 64 lanes
    int a = (l < NB) ? blkSums[l] : 0;
    int b = (64 + l < NB) ? blkSums[64 + l] : 0;
    int ia = a, ib = b;
    for (int o = 1; o < 64; o <<= 1) {
        int t0 = __shfl_up(ia, o, 64);
        if (l >= o) ia += t0;
        int t1 = __shfl_up(ib, o, 64);
        if (l >= o) ib += t1;
    }
    int tot0 = __shfl(ia, 63, 64);
    if (l < NB) blkOff[l] = ia - a;
    if (64 + l < NB) blkOff[64 + l] = tot0 + ib - b;
}

__global__ __launch_bounds__(256) void scanC_kernel(
    const int* __restrict__ cnt, int M, const int* __restrict__ blkOff,
    int* __restrict__ offs, int* __restrict__ curs)
{
    __shared__ int s[256];
    int b = blockIdx.x, t = threadIdx.x;
    int base = b * SCAN_CHUNK + t * 16;
    int loc[16];
    int tot = 0;
    #pragma unroll
    for (int i = 0; i < 16; i++) {
        int idx = base + i;
        int v = (idx < M) ? cnt[idx] : 0;
        loc[i] = tot; tot += v;
    }
    s[t] = tot; __syncthreads();
    for (int off = 1; off < 256; off <<= 1) {
        int v = (t >= off) ? s[t - off] : 0;
        __syncthreads();
        s[t] += v;
        __syncthreads();
    }
    int texc = s[t] - tot;           // exclusive prefix of this thread
    int bb = blkOff[b];
    #pragma unroll
    for (int i = 0; i < 16; i++) {
        int idx = base + i;
        if (idx < M) { int o = bb + texc + loc[i]; offs[idx] = o; curs[idx] = o; }
    }
}

// scatter: per-edge packed (src*8 + rel, weight) as int2 -> ONE 8B scattered
// store per edge. Decoded by gather_lut (layer 1) and gather_acc (layer 2).
__global__ __launch_bounds__(256) void scatter_kernel(
    const int* __restrict__ src, const int* __restrict__ dst, const int* __restrict__ et,
    const int* __restrict__ cnts, int* __restrict__ cursors,
    int2* __restrict__ epk)
{
    int i = blockIdx.x * 256 + threadIdx.x;
    if (i < EE) {
        int r = et[i];
        int b = dst[i] * RR + r;
        int pos = atomicAdd(&cursors[b], 1);
        int2 p;
        p.x = src[i] * 8 + r;
        p.y = __float_as_int(1.0f / (float)cnts[b]);
        epk[pos] = p;
    }
}

// ---------------- dense bf16 MFMA GEMM: frag-packed DOUBLE-buffered LDS (R14) ----
// Layer 2 + gate only (layer 1 is LUT-based). Frag-packed XOR-swizzled LDS,
// true double buffer (64KB), one barrier/K-tile, pinned prefetch,
// T1 bijective XCD remap. MODE 0: plain; 1: +bias; 2: +hacc+bias+sigmoid.
template<int K, int MODE>
__global__ __launch_bounds__(256) void dense_gemm(
    const ushort* __restrict__ A,    // [M][K] bf16
    const ushort* __restrict__ Bt,   // [NCOL][K] bf16 (rows = C cols)
    const float* __restrict__ bias,  // [NCOL] (MODE>=1)
    const ushort* __restrict__ haccp,// [M][256] bf16 (MODE==2)
    ushort* __restrict__ C,          // [M][NCOL] bf16
    int M, int NCOL)
{
    constexpr int NKT = K / 64;
    __shared__ __attribute__((aligned(16))) ushort Al[2][128 * 64];  // 2x16 KB
    __shared__ __attribute__((aligned(16))) ushort Bl[2][128 * 64];  // 2x16 KB

    // ---- T1: bijective XCD-chunked remap (m204) ----
    const int nwg  = gridDim.x * gridDim.y;
    const int flat = blockIdx.y * gridDim.x + blockIdx.x;
    const int q8 = nwg >> 3, r8 = nwg & 7;
    const int xcd = flat & 7, pos = flat >> 3;
    const int vid = ((xcd < r8) ? xcd * (q8 + 1) : r8 * (q8 + 1) + (xcd - r8) * q8) + pos;
    const int m0  = (vid / gridDim.x) * 128;
    const int n0  = (vid % gridDim.x) * 128;

    const int t    = threadIdx.x;
    const int lane = t & 63;
    const int wv   = t >> 6;
    const int wr   = (wv >> 1) * 64;  // wave row offset
    const int wc   = (wv & 1) * 64;   // wave col offset
    const int l15  = lane & 15;
    const int kg   = lane >> 4;

    // staging decomposition: thread covers rows sr+32i, global elems [sc, sc+8)
    const int sr = t >> 3;
    const int sc = (t & 7) * 8;
    const int g0 = sc,      g1 = sc + 4;
    const int s0 = ((g0 >> 5) << 2) + ((g0 & 15) >> 2), h0_ = (g0 >> 4) & 1;
    const int s1 = ((g1 >> 5) << 2) + ((g1 & 15) >> 2), h1_ = (g1 >> 4) & 1;

    int arow[4], brow[4];
    #pragma unroll
    for (int i = 0; i < 4; i++) {
        int r = sr + i * 32;
        arow[i] = min(m0 + r, M - 1);
        brow[i] = n0 + r;
    }

    uint4 av[4], bv[4];
    auto SLOAD = [&](int kt) {
        const ushort* Ak = A + kt * 64 + sc;
        const ushort* Bk = Bt + kt * 64 + sc;
        #pragma unroll
        for (int i = 0; i < 4; i++) av[i] = *(const uint4*)(Ak + (size_t)arow[i] * K);
        #pragma unroll
        for (int i = 0; i < 4; i++) bv[i] = *(const uint4*)(Bk + (size_t)brow[i] * K);
    };
    auto SWRITE = [&](int buf) {
        #pragma unroll
        for (int i = 0; i < 4; i++) {
            int row = sr + i * 32;
            int rx  = row & 7;
            int o0  = row * 64 + (((s0 ^ rx) << 3) + h0_ * 4);
            int o1  = row * 64 + (((s1 ^ rx) << 3) + h1_ * 4);
            *(uint2*)&Al[buf][o0] = make_uint2(av[i].x, av[i].y);
            *(uint2*)&Al[buf][o1] = make_uint2(av[i].z, av[i].w);
            *(uint2*)&Bl[buf][o0] = make_uint2(bv[i].x, bv[i].y);
            *(uint2*)&Bl[buf][o1] = make_uint2(bv[i].z, bv[i].w);
        }
    };

    f32x4 acc[4][4];
    #pragma unroll
    for (int mt = 0; mt < 4; mt++)
        #pragma unroll
        for (int nt = 0; nt < 4; nt++) acc[mt][nt] = (f32x4){0.f, 0.f, 0.f, 0.f};

    union FR { bf16x8 v; uint u[4]; };

    SLOAD(0);
    SWRITE(0);
    __syncthreads();

    for (int kt = 0; kt < NKT; kt++) {
        const int cur = kt & 1;
        if (kt + 1 < NKT) {
            SLOAD(kt + 1);                       // issue prefetch...
            __builtin_amdgcn_sched_barrier(0);   // ...pinned before the MFMA phase
        }
        const ushort* Ap = Al[cur];
        const ushort* Bp = Bl[cur];
        #pragma unroll
        for (int kb = 0; kb < 2; kb++) {
            const int s = kb * 4 + kg;
            FR a[4], b[4];
            #pragma unroll
            for (int mt = 0; mt < 4; mt++) {
                int row = wr + mt * 16 + l15;
                uint4 va = *(const uint4*)&Ap[row * 64 + ((s ^ (row & 7)) << 3)];
                a[mt].u[0] = va.x; a[mt].u[1] = va.y; a[mt].u[2] = va.z; a[mt].u[3] = va.w;
            }
            #pragma unroll
            for (int nt = 0; nt < 4; nt++) {
                int row = wc + nt * 16 + l15;
                uint4 vb = *(const uint4*)&Bp[row * 64 + ((s ^ (row & 7)) << 3)];
                b[nt].u[0] = vb.x; b[nt].u[1] = vb.y; b[nt].u[2] = vb.z; b[nt].u[3] = vb.w;
            }
            #pragma unroll
            for (int nt = 0; nt < 4; nt++)
                #pragma unroll
                for (int mt = 0; mt < 4; mt++)
                    acc[mt][nt] = __builtin_amdgcn_mfma_f32_16x16x32_bf16(a[mt].v, b[nt].v, acc[mt][nt], 0, 0, 0);
        }
        if (kt + 1 < NKT) {
            SWRITE(cur ^ 1);    // other buffer: safe vs concurrent readers of `cur`
            __syncthreads();    // new tile visible for next iteration
        }
    }

    // epilogue: C/D layout col=lane&15, row=(lane>>4)*4+i  (direct stores)
    #pragma unroll
    for (int nt = 0; nt < 4; nt++) {
        int col = n0 + wc + nt * 16 + l15;
        float bvv = (MODE >= 1) ? bias[col] : 0.f;
        #pragma unroll
        for (int mt = 0; mt < 4; mt++) {
            #pragma unroll
            for (int i = 0; i < 4; i++) {
                int row = m0 + wr + mt * 16 + kg * 4 + i;
                if (row < M) {
                    float v = acc[mt][nt][i] + bvv;
                    if (MODE == 2) {
                        v += bf2f(haccp[(size_t)row * DL + col]);
                        v = sigmoidf_(v);
                    }
                    C[(size_t)row * NCOL + col] = f2bf(v);
                }
            }
        }
    }
}

// ---------------- flat CSR gather-accumulate over relations [relStart, relEnd) ----
// epk packs (src*8+rel, weight); hrc index decoded per edge. Half-wave per
// node, 8 cols (16B) per lane; edges in 4-wide batches.
__global__ __launch_bounds__(256) void gather_acc(
    const ushort* __restrict__ hrc,  // [N][chc] bf16
    const int2* __restrict__ epk,
    const int* __restrict__ offs,    // [N*8]
    ushort* __restrict__ hacc,       // [N][256] bf16
    int relStart, int relEnd, int first, int chc, int mask)
{
    int t = threadIdx.x;
    int slot = t >> 5;               // 0..7
    int l = t & 31;
    int n = blockIdx.x * 8 + slot;
    if (n >= NN) return;
    int e    = offs[n * 8 + relStart];
    int endE = (relEnd == 8 && n == NN - 1) ? EE : offs[n * 8 + relEnd];
    int c = l * 8;

    float acc[8];
    if (first) {
        #pragma unroll
        for (int q = 0; q < 8; q++) acc[q] = 0.f;
    } else {
        uint4 a = *(const uint4*)&hacc[(size_t)n * DL + c];
        unp8(acc, a);
    }

    for (; e < endE; e += 4) {
        int e1 = min(e + 1, endE - 1);
        int e2 = min(e + 2, endE - 1);
        int e3 = min(e + 3, endE - 1);
        int2 p0 = epk[e], p1 = epk[e1], p2 = epk[e2], p3 = epk[e3];
        float w0 = __int_as_float(p0.y);
        float w1 = (e + 1 < endE) ? __int_as_float(p1.y) : 0.f;
        float w2 = (e + 2 < endE) ? __int_as_float(p2.y) : 0.f;
        float w3 = (e + 3 < endE) ? __int_as_float(p3.y) : 0.f;
        int i0 = (p0.x >> 3) * chc + ((p0.x & 7) & mask) * DL;
        int i1 = (p1.x >> 3) * chc + ((p1.x & 7) & mask) * DL;
        int i2 = (p2.x >> 3) * chc + ((p2.x & 7) & mask) * DL;
        int i3 = (p3.x >> 3) * chc + ((p3.x & 7) & mask) * DL;
        uint4 v0 = *(const uint4*)&hrc[(size_t)i0 + c];
        uint4 v1 = *(const uint4*)&hrc[(size_t)i1 + c];
        uint4 v2 = *(const uint4*)&hrc[(size_t)i2 + c];
        uint4 v3 = *(const uint4*)&hrc[(size_t)i3 + c];
        accw8(acc, v0, w0); accw8(acc, v1, w1);
        accw8(acc, v2, w2); accw8(acc, v3, w3);
    }

    *(uint4*)&hacc[(size_t)n * DL + c] = pack8bf(acc);
}

// ---------------- BatchNorm stats over hg1 columns (vectorized) ----------------
__global__ __launch_bounds__(256) void bnstats_kernel(
    const ushort* __restrict__ hg1, float* __restrict__ colsum, float* __restrict__ colsum2)
{
    __shared__ float ss[8][256], ss2[8][256];
    int t = threadIdx.x;
    int g = t >> 5, l = t & 31;
    int c = l * 8;
    constexpr int RPB = (NN + 255) / 256;   // 196
    int row0 = blockIdx.x * RPB;
    int rend = min(row0 + RPB, NN);
    float s[8], s2[8];
    #pragma unroll
    for (int q = 0; q < 8; q++) { s[q] = 0.f; s2[q] = 0.f; }
    for (int r = row0 + g; r < rend; r += 8) {
        uint4 v = *(const uint4*)&hg1[(size_t)r * DL + c];
        float f[8]; unp8(f, v);
        #pragma unroll
        for (int q = 0; q < 8; q++) { s[q] += f[q]; s2[q] += f[q] * f[q]; }
    }
    #pragma unroll
    for (int q = 0; q < 8; q++) { ss[g][c + q] = s[q]; ss2[g][c + q] = s2[q]; }
    __syncthreads();
    float ts = 0.f, ts2 = 0.f;
    #pragma unroll
    for (int gg = 0; gg < 8; gg++) { ts += ss[gg][t]; ts2 += ss2[gg][t]; }
    atomicAdd(&colsum[t], ts);
    atomicAdd(&colsum2[t], ts2);
}

__global__ void bnfinal_kernel(
    const float* __restrict__ colsum, const float* __restrict__ colsum2,
    const float* __restrict__ gamma, float* __restrict__ mu, float* __restrict__ aa)
{
    int c = threadIdx.x;
    if (c < DL) {
        float m = colsum[c] / (float)NN;
        float var = colsum2[c] / (float)NN - m * m;
        mu[c] = m;
        aa[c] = rsqrtf(var + 1e-5f) * gamma[c];
    }
}

// ---------------- gate = relu(BN(hg1)) @ Wg2 + bg2 ; segment max ----------------
__global__ __launch_bounds__(256) void gate_kernel(
    const ushort* __restrict__ hg1, const float* __restrict__ mu,
    const float* __restrict__ aa, const float* __restrict__ beta,
    const float* __restrict__ Wg2, const float* __restrict__ bg2,
    const int* __restrict__ batch,
    float* __restrict__ gate, unsigned* __restrict__ gmaxu)
{
    int lane = threadIdx.x & 63;
    int wid = (blockIdx.x * blockDim.x + threadIdx.x) >> 6;
    int nw = (gridDim.x * blockDim.x) >> 6;
    int per = (NN + nw - 1) / nw;
    int n0 = wid * per;
    if (n0 >= NN) return;
    int n1 = min(n0 + per, NN);
    float bg2v = bg2[0];
    float lmax = -3.4e38f;
    int curb = batch[n0];
    for (int n = n0; n < n1; n++) {
        float s = 0.f;
        #pragma unroll
        for (int c = 0; c < 4; c++) {
            int d = c * 64 + lane;
            float v = bf2f(hg1[(size_t)n * DL + d]);
            float xn = (v - mu[d]) * aa[d] + beta[d];
            xn = fmaxf(xn, 0.f);
            s += xn * Wg2[d];
        }
        #pragma unroll
        for (int o = 32; o > 0; o >>= 1) s += __shfl_down(s, o, 64);
        if (lane == 0) {
            float g = s + bg2v;
            gate[n] = g;
            int b = batch[n];
            if (b != curb) {
                atomicMax(&gmaxu[curb], fenc(lmax));
                lmax = -3.4e38f; curb = b;
            }
            lmax = fmaxf(lmax, g);
        }
    }
    if (lane == 0) atomicMax(&gmaxu[curb], fenc(lmax));
}

// ---------------- exp + per-graph denom (contiguous 4-node runs/thread) ----
__global__ __launch_bounds__(256) void expdenom_kernel(
    const float* __restrict__ gate, const int* __restrict__ batch,
    const unsigned* __restrict__ gmaxu, float* __restrict__ ealpha, float* __restrict__ denom)
{
    int tid = blockIdx.x * 256 + threadIdx.x;
    int i0 = tid * 4;
    if (i0 >= NN) return;
    int i1 = min(i0 + 4, NN);
    int curb = batch[i0];
    float m = fdec(gmaxu[curb]);
    float lsum = 0.f;
    for (int i = i0; i < i1; i++) {
        int b = batch[i];
        if (b != curb) {
            atomicAdd(&denom[curb], lsum);
            lsum = 0.f; curb = b; m = fdec(gmaxu[b]);
        }
        float ex = expf(gate[i] - m);
        ealpha[i] = ex;
        lsum += ex;
    }
    atomicAdd(&denom[curb], lsum);
}

// ---------------- pooled[g] = sum (e/denom) * h2[n] (batch sorted, vectorized) ----
__global__ __launch_bounds__(256) void pool_kernel(
    const ushort* __restrict__ h2, const float* __restrict__ ealpha,
    const float* __restrict__ denom, const int* __restrict__ batch,
    float* __restrict__ pooled)
{
    int t = threadIdx.x;
    int g = t >> 5, l = t & 31;
    int c = l * 8;
    int row0 = blockIdx.x * 128 + g * 16;
    if (row0 >= NN) return;
    int rend = min(row0 + 16, NN);
    float acc[8];
    #pragma unroll
    for (int q = 0; q < 8; q++) acc[q] = 0.f;
    int curg = batch[row0];
    for (int r = row0; r < rend; r++) {
        int gb = batch[r];
        if (gb != curg) {
            float inv = 1.0f / denom[curg];
            #pragma unroll
            for (int q = 0; q < 8; q++) atomicAdd(&pooled[curg * DL + c + q], acc[q] * inv);
            #pragma unroll
            for (int q = 0; q < 8; q++) acc[q] = 0.f;
            curg = gb;
        }
        float w = ealpha[r];
        uint4 v = *(const uint4*)&h2[(size_t)r * DL + c];
        accw8(acc, v, w);
    }
    float inv = 1.0f / denom[curg];
    #pragma unroll
    for (int q = 0; q < 8; q++) atomicAdd(&pooled[curg * DL + c + q], acc[q] * inv);
}

__global__ void head_kernel(
    const float* __restrict__ pooled, const float* __restrict__ Wgl,
    const float* __restrict__ bgl, float* __restrict__ out)
{
    int g = blockIdx.x;
    int lane = threadIdx.x;           // 64
    float s = 0.f;
    #pragma unroll
    for (int c = 0; c < 4; c++) {
        int d = c * 64 + lane;
        s += pooled[g * DL + d] * Wgl[d];
    }
    #pragma unroll
    for (int o = 32; o > 0; o >>= 1) s += __shfl_down(s, o, 64);
    if (lane == 0) out[g] = sigmoidf_(s + bgl[0]);
}

extern "C" void kernel_launch(void* const* d_in, const int* in_sizes, int n_in,
                              void* d_out, int out_size, void* d_ws, size_t ws_size,
                              hipStream_t stream)
{
    const int* x      = (const int*)d_in[0];
    const int* ei     = (const int*)d_in[1];
    const int* etype  = (const int*)d_in[2];
    const int* batch  = (const int*)d_in[3];
    const float* e0   = (const float*)d_in[4];
    const float* e1   = (const float*)d_in[5];
    const float* e2   = (const float*)d_in[6];
    const float* e3   = (const float*)d_in[7];
    const float* e4   = (const float*)d_in[8];
    const float* e5   = (const float*)d_in[9];
    const float* W1   = (const float*)d_in[10];
    const float* root1= (const float*)d_in[11];
    const float* b1   = (const float*)d_in[12];
    const float* W2   = (const float*)d_in[13];
    const float* root2= (const float*)d_in[14];
    const float* b2   = (const float*)d_in[15];
    const float* Wg1  = (const float*)d_in[16];
    const float* bg1  = (const float*)d_in[17];
    const float* gamma= (const float*)d_in[18];
    const float* beta = (const float*)d_in[19];
    const float* Wg2  = (const float*)d_in[20];
    const float* bg2  = (const float*)d_in[21];
    const float* Wgl  = (const float*)d_in[22];
    const float* bgl  = (const float*)d_in[23];
    float* out = (float*)d_out;

    const int* esrc_in = ei;          // edge_index[0]
    const int* edst_in = ei + EE;     // edge_index[1]

    char* ws = (char*)d_ws;
    size_t off = 0;
    auto alloc = [&](size_t b) -> char* {
        char* p = ws + off;
        off += (b + 255) & ~(size_t)255;
        return p;
    };
    ushort* h2     = (ushort*)alloc((size_t)NN * DL * 2);    // 25.6 MB
    ushort* h1     = (ushort*)alloc((size_t)NN * DL * 2);    // 25.6 MB
    ushort* hacc   = (ushort*)alloc((size_t)NN * DL * 2);    // 25.6 MB bf16
    size_t zstart = off;                                     // ---- zeroed region ----
    int*      counts  = (int*)alloc((size_t)NN * RR * 4);
    float*    colsum  = (float*)alloc(DL * 4);
    float*    colsum2 = (float*)alloc(DL * 4);
    unsigned* gmaxu   = (unsigned*)alloc(GG * 4);
    float*    denom   = (float*)alloc(GG * 4);
    float*    pooled  = (float*)alloc((size_t)GG * DL * 4);
    size_t zbytes = off - zstart;                            // ---- end zeroed ----
    int*   offs    = (int*)alloc((size_t)NN * RR * 4);
    int*   cursors = (int*)alloc((size_t)NN * RR * 4);
    int2*  epk     = (int2*)alloc((size_t)EE * 8);           // packed (src*8+r, weight)
    int*   blkSums = (int*)alloc(512);
    int*   blkOff  = (int*)alloc(512);
    float* mu      = (float*)alloc(DL * 4);
    float* aa      = (float*)alloc(DL * 4);
    float* gate    = (float*)alloc((size_t)NN * 4);
    float* ealpha  = (float*)alloc((size_t)NN * 4);
    ushort* Tlut   = (ushort*)alloc((size_t)NCR * 9 * DL * 2); // 230.4 KB LUT
    ushort* WbT2   = (ushort*)alloc((size_t)9 * DL * DL * 2);  // 1.18 MB
    ushort* WbTg   = (ushort*)alloc((size_t)1 * DL * DL * 2);  // 131 KB

    // hrc LAST (bf16, layer-2 messages only now): prefer 4-relation chunks.
    int npc;
    ushort* hrc;
    {
        size_t need4 = ((size_t)NN * 4 * DL * 2 + 255) & ~(size_t)255;
        size_t need2 = ((size_t)NN * 2 * DL * 2 + 255) & ~(size_t)255;
        if (off + need4 <= ws_size)      { npc = 4; hrc = (ushort*)alloc((size_t)NN * 4 * DL * 2); }
        else if (off + need2 <= ws_size) { npc = 2; hrc = (ushort*)alloc((size_t)NN * 2 * DL * 2); }
        else return;   // fail loudly (wrong output) rather than corrupt
    }
    const int chc = npc * DL;

    ushort* hg1 = hrc;    // hrc dead after layer2's last gather

    hipMemsetAsync(ws + zstart, 0, zbytes, stream);

    // layer-1 LUT + layer-2/gate weight transposes
    lutbuild_kernel<<<NCR * 9, 256, 0, stream>>>(e0, e1, e2, e3, e4, e5, W1, root1, Tlut);
    count_kernel<<<(EE + 255) / 256, 256, 0, stream>>>(edst_in, etype, counts);
    {
        int tot2 = 9 * DL * DL;
        cvtT_kernel<<<(tot2 + 255) / 256, 256, 0, stream>>>(W2, root2, WbT2, RR, DL);
        int totg = 1 * DL * DL;
        cvtT_kernel<<<(totg + 255) / 256, 256, 0, stream>>>(nullptr, Wg1, WbTg, 0, DL);
    }

    const int M = NN * RR;
    const int NB = (M + SCAN_CHUNK - 1) / SCAN_CHUNK;   // 98
    scanA_kernel<<<NB, 256, 0, stream>>>(counts, M, blkSums);
    scanB_kernel<<<1, 64, 0, stream>>>(blkSums, NB, blkOff);
    scanC_kernel<<<NB, 256, 0, stream>>>(counts, M, blkOff, offs, cursors);
    scatter_kernel<<<(EE + 255) / 256, 256, 0, stream>>>(esrc_in, edst_in, etype, counts, cursors, epk);

    const int MT = (NN + 127) / 128;   // 391 M-tiles
    const dim3 GC(npc * 2, MT), G2(2, MT);
    const int ABLK = (NN + 7) / 8;

    // ---- layer 1: direct-LUT gather (no hrc materialization), 2 relation halves ----
    {
        dim3 GL((NN + 31) / 32, 4);
        gather_lut<<<GL, 256, 0, stream>>>(Tlut, x, epk, offs, hacc, 0, 1);
        gather_lut<<<GL, 256, 0, stream>>>(Tlut, x, epk, offs, hacc, 4, 0);
    }
    lutfin_kernel<<<512, 256, 0, stream>>>(Tlut, x, hacc, b1, h1);

    // ---- layer 2 (IN=256), GEMM-based ----
    for (int c0 = 0; c0 < RR; c0 += npc) {
        dense_gemm<DL, 0><<<GC, 256, 0, stream>>>(h1, WbT2 + (size_t)c0 * DL * DL, nullptr, nullptr, hrc, NN, chc);
        gather_acc<<<ABLK, 256, 0, stream>>>(hrc, epk, offs, hacc, c0, c0 + npc, c0 == 0, chc, npc - 1);
    }
    dense_gemm<DL, 2><<<G2, 256, 0, stream>>>(h1, WbT2 + (size_t)8 * DL * DL, b2, hacc, h2, NN, DL);

    // ---- gate linear (no act; BN follows) ----
    dense_gemm<DL, 1><<<G2, 256, 0, stream>>>(h2, WbTg, bg1, nullptr, hg1, NN, DL);

    bnstats_kernel<<<256, 256, 0, stream>>>(hg1, colsum, colsum2);
    bnfinal_kernel<<<1, 256, 0, stream>>>(colsum, colsum2, gamma, mu, aa);
    gate_kernel<<<512, 256, 0, stream>>>(hg1, mu, aa, beta, Wg2, bg2, batch, gate, gmaxu);
    expdenom_kernel<<<((NN + 3) / 4 + 255) / 256, 256, 0, stream>>>(gate, batch, gmaxu, ealpha, denom);
    pool_kernel<<<(NN + 127) / 128, 256, 0, stream>>>(h2, ealpha, denom, batch, pooled);
    head_kernel<<<GG, 64, 0, stream>>>(pooled, Wgl, bgl, out);
}

// Round 21
// 618.051 us; speedup vs baseline: 1.0330x; 1.0330x over previous
//
#include <hip/hip_runtime.h>
#include <hip/hip_bf16.h>
#include <cstdint>

#define NN 50000
#define EE 800000
#define RR 8
#define GG 128
#define D0 384
#define DL 256
#define NCR 50       // total embedding rows: 33+5+3+4+2+3

typedef __attribute__((ext_vector_type(8))) short bf16x8;
typedef __attribute__((ext_vector_type(4))) float f32x4;

__device__ __forceinline__ float sigmoidf_(float x) { return 1.0f / (1.0f + expf(-x)); }

__device__ __forceinline__ ushort f2bf(float f) {
    uint u = __float_as_uint(f);
    u += 0x7fffu + ((u >> 16) & 1u);
    return (ushort)(u >> 16);
}
__device__ __forceinline__ uint pack2bf(float lo, float hi) {
    return (uint)f2bf(lo) | ((uint)f2bf(hi) << 16);
}
__device__ __forceinline__ float bf2f(ushort u) {
    return __uint_as_float((uint)u << 16);
}

// acc[0..7] += w * bf16x8(v)
__device__ __forceinline__ void accw8(float* s, uint4 a, float w) {
    s[0] += w * __uint_as_float(a.x << 16);
    s[1] += w * __uint_as_float(a.x & 0xffff0000u);
    s[2] += w * __uint_as_float(a.y << 16);
    s[3] += w * __uint_as_float(a.y & 0xffff0000u);
    s[4] += w * __uint_as_float(a.z << 16);
    s[5] += w * __uint_as_float(a.z & 0xffff0000u);
    s[6] += w * __uint_as_float(a.w << 16);
    s[7] += w * __uint_as_float(a.w & 0xffff0000u);
}

// unpack 8 bf16 to fp32
__device__ __forceinline__ void unp8(float* f, uint4 a) {
    f[0] = __uint_as_float(a.x << 16);
    f[1] = __uint_as_float(a.x & 0xffff0000u);
    f[2] = __uint_as_float(a.y << 16);
    f[3] = __uint_as_float(a.y & 0xffff0000u);
    f[4] = __uint_as_float(a.z << 16);
    f[5] = __uint_as_float(a.z & 0xffff0000u);
    f[6] = __uint_as_float(a.w << 16);
    f[7] = __uint_as_float(a.w & 0xffff0000u);
}
__device__ __forceinline__ uint4 pack8bf(const float* f) {
    uint4 p;
    p.x = pack2bf(f[0], f[1]);
    p.y = pack2bf(f[2], f[3]);
    p.z = pack2bf(f[4], f[5]);
    p.w = pack2bf(f[6], f[7]);
    return p;
}

// order-preserving float->uint encoding for atomicMax
__device__ __forceinline__ unsigned fenc(float x) {
    unsigned u = __float_as_uint(x);
    return (u & 0x80000000u) ? ~u : (u | 0x80000000u);
}
__device__ __forceinline__ float fdec(unsigned u) {
    unsigned b = (u & 0x80000000u) ? (u & 0x7fffffffu) : ~u;
    return __uint_as_float(b);
}

// ---------------- layer-1 LUT build: T[cr][r][col] = emb_row(cr) @ W1[r, slice] ----
__global__ __launch_bounds__(256) void lutbuild_kernel(
    const float* __restrict__ e0, const float* __restrict__ e1,
    const float* __restrict__ e2, const float* __restrict__ e3,
    const float* __restrict__ e4, const float* __restrict__ e5,
    const float* __restrict__ W1, const float* __restrict__ root1,
    ushort* __restrict__ T)          // [50][9][256] bf16
{
    int b = blockIdx.x;              // 0..449
    int cr = b / 9;
    int r  = b - cr * 9;
    int t, c;
    if      (cr < 33) { t = 0; c = cr; }
    else if (cr < 38) { t = 1; c = cr - 33; }
    else if (cr < 41) { t = 2; c = cr - 38; }
    else if (cr < 45) { t = 3; c = cr - 41; }
    else if (cr < 47) { t = 4; c = cr - 45; }
    else              { t = 5; c = cr - 47; }
    const float* emb;
    switch (t) {
        case 0: emb = e0; break; case 1: emb = e1; break; case 2: emb = e2; break;
        case 3: emb = e3; break; case 4: emb = e4; break; default: emb = e5; break;
    }
    const float* er = emb + c * 64;
    int col = threadIdx.x;           // 256
    const float* Wb = (r < 8) ? (W1 + ((size_t)r * D0 + t * 64) * DL + col)
                              : (root1 + (size_t)(t * 64) * DL + col);
    float s = 0.f;
    #pragma unroll 8
    for (int k = 0; k < 64; k++) s += er[k] * Wb[(size_t)k * DL];
    T[(size_t)(cr * 9 + r) * DL + col] = f2bf(s);
}

// ---------------- layer-1 message production via LDS-cached LUT-sum ----------------
// Block covers ONE relation (blockIdx.y) x ONE col half (blockIdx.z):
// LDS = 50*128*2B = 12.8 KB -> ~8 blocks/CU (R18's 25.6 KB capped at 6;
// write-bound-by-occupancy per R17/R18 lineage). 16 nodes per block-iter.
__global__ __launch_bounds__(256) void lutsum_kernel(
    const ushort* __restrict__ T,    // [50][9][256] bf16
    const int* __restrict__ x,       // [N][6]
    ushort* __restrict__ hrc,        // [N][chc] bf16
    int c0, int chc)
{
    __shared__ ushort Ts[NCR * 128];       // 12.8 KB
    const int rr   = blockIdx.y;           // relation within chunk
    const int half = blockIdx.z;           // col half 0..1
    int t = threadIdx.x;
    for (int i = t; i < NCR * 128; i += 256) {
        int cr = i >> 7, col = i & 127;
        Ts[i] = T[(size_t)(cr * 9 + c0 + rr) * 256 + half * 128 + col];
    }
    __syncthreads();

    const int slot = t >> 4;          // 16 nodes per block-iteration
    const int l    = t & 15;
    const int c    = l * 8;           // col within half
    const int colbase = rr * 256 + half * 128 + c;

    for (int base = blockIdx.x * 16; base < NN; base += gridDim.x * 16) {
        int n = base + slot;
        if (n < NN) {
            const int* xp = x + n * 6;
            const int cumc[6] = {0, 33, 38, 41, 45, 47};
            float acc[8];
            #pragma unroll
            for (int q = 0; q < 8; q++) acc[q] = 0.f;
            #pragma unroll
            for (int tb = 0; tb < 6; tb++) {
                int cr = cumc[tb] + xp[tb];
                uint4 v = *(const uint4*)&Ts[cr * 128 + c];
                accw8(acc, v, 1.0f);
            }
            *(uint4*)&hrc[(size_t)n * chc + colbase] = pack8bf(acc);
        }
    }
}

// ---------------- layer-1 finalize: h1 = sigmoid(LUT_root + hacc + b1) ----------------
__global__ __launch_bounds__(256) void lutfin_kernel(
    const ushort* __restrict__ T, const int* __restrict__ x,
    const ushort* __restrict__ hacc, const float* __restrict__ b1,
    ushort* __restrict__ h1)
{
    __shared__ ushort Ts[NCR * 256];  // root slice (r=8), 25.6 KB
    int t = threadIdx.x;
    for (int i = t; i < NCR * 256; i += 256) {
        int cr = i >> 8, col = i & 255;
        Ts[i] = T[(size_t)(cr * 9 + 8) * 256 + col];
    }
    __syncthreads();

    const int slot = t >> 5;          // 8 nodes per block-iteration
    const int l = t & 31;
    const int c = l * 8;

    for (int base = blockIdx.x * 8; base < NN; base += gridDim.x * 8) {
        int n = base + slot;
        if (n < NN) {
            const int* xp = x + n * 6;
            const int cumc[6] = {0, 33, 38, 41, 45, 47};
            float acc[8];
            float4 b0 = *(const float4*)&b1[c];
            float4 bb = *(const float4*)&b1[c + 4];
            acc[0] = b0.x; acc[1] = b0.y; acc[2] = b0.z; acc[3] = b0.w;
            acc[4] = bb.x; acc[5] = bb.y; acc[6] = bb.z; acc[7] = bb.w;
            #pragma unroll
            for (int tb = 0; tb < 6; tb++) {
                int cr = cumc[tb] + xp[tb];
                uint4 v = *(const uint4*)&Ts[cr * 256 + c];
                accw8(acc, v, 1.0f);
            }
            uint4 hv = *(const uint4*)&hacc[(size_t)n * DL + c];
            float hf[8]; unp8(hf, hv);
            #pragma unroll
            for (int q = 0; q < 8; q++) acc[q] = sigmoidf_(acc[q] + hf[q]);
            *(uint4*)&h1[(size_t)n * DL + c] = pack8bf(acc);
        }
    }
}

// ---------------- weight convert + transpose: WbT[r*256+n][k] = bf16(W[r][k][n]) ----------------
__global__ __launch_bounds__(256) void cvtT_kernel(
    const float* __restrict__ W, const float* __restrict__ root,
    ushort* __restrict__ WbT, int nrel, int IN)
{
    int idx = blockIdx.x * 256 + threadIdx.x;
    int tot = (nrel + 1) * DL * IN;
    if (idx >= tot) return;
    int k = idx % IN;
    int rn = idx / IN;
    int n = rn % DL;
    int r = rn / DL;
    float v = (r < nrel) ? W[((size_t)r * IN + k) * DL + n] : root[(size_t)k * DL + n];
    WbT[idx] = f2bf(v);
}

// ---------------- CSR build ----------------
__global__ __launch_bounds__(256) void count_kernel(
    const int* __restrict__ dst, const int* __restrict__ et, int* __restrict__ counts)
{
    int i = blockIdx.x * 256 + threadIdx.x;
    if (i < EE) atomicAdd(&counts[dst[i] * RR + et[i]], 1);
}

#define SCAN_CHUNK 4096
__global__ __launch_bounds__(256) void scanA_kernel(const int* __restrict__ cnt, int M, int* __restrict__ blkSums)
{
    __shared__ int s[256];
    int b = blockIdx.x, t = threadIdx.x;
    int base = b * SCAN_CHUNK + t * 16;
    int tot = 0;
    #pragma unroll
    for (int i = 0; i < 16; i++) { int idx = base + i; if (idx < M) tot += cnt[idx]; }
    s[t] = tot; __syncthreads();
    for (int off = 128; off > 0; off >>= 1) {
        if (t < off) s[t] += s[t + off];
        __syncthreads();
    }
    if (t == 0) blkSums[b] = s[0];
}

// wave-parallel exclusive scan over NB<=128 block sums
__global__ void scanB_kernel(const int* __restrict__ blkSums, int NB, int* __restrict__ blkOff)
{
    int l = threadIdx.x;              // 64 lanes
    int a = (l < NB) ? blkSums[l] : 0;
    int b = (64 + l < NB) ? blkSums[64 + l] : 0;
    int ia = a, ib = b;
    for (int o = 1; o < 64; o <<= 1) {
        int t0 = __shfl_up(ia, o, 64);
        if (l >= o) ia += t0;
        int t1 = __shfl_up(ib, o, 64);
        if (l >= o) ib += t1;
    }
    int tot0 = __shfl(ia, 63, 64);
    if (l < NB) blkOff[l] = ia - a;
    if (64 + l < NB) blkOff[64 + l] = tot0 + ib - b;
}

__global__ __launch_bounds__(256) void scanC_kernel(
    const int* __restrict__ cnt, int M, const int* __restrict__ blkOff,
    int* __restrict__ offs, int* __restrict__ curs)
{
    __shared__ int s[256];
    int b = blockIdx.x, t = threadIdx.x;
    int base = b * SCAN_CHUNK + t * 16;
    int loc[16];
    int tot = 0;
    #pragma unroll
    for (int i = 0; i < 16; i++) {
        int idx = base + i;
        int v = (idx < M) ? cnt[idx] : 0;
        loc[i] = tot; tot += v;
    }
    s[t] = tot; __syncthreads();
    for (int off = 1; off < 256; off <<= 1) {
        int v = (t >= off) ? s[t - off] : 0;
        __syncthreads();
        s[t] += v;
        __syncthreads();
    }
    int texc = s[t] - tot;           // exclusive prefix of this thread
    int bb = blkOff[b];
    #pragma unroll
    for (int i = 0; i < 16; i++) {
        int idx = base + i;
        if (idx < M) { int o = bb + texc + loc[i]; offs[idx] = o; curs[idx] = o; }
    }
}

// scatter: per-edge packed (gather index, weight) as int2 -> ONE 8B scattered
// store per edge. idx = src*chc + (r & mask)*256.
__global__ __launch_bounds__(256) void scatter_kernel(
    const int* __restrict__ src, const int* __restrict__ dst, const int* __restrict__ et,
    const int* __restrict__ cnts, int* __restrict__ cursors,
    int2* __restrict__ epk, int chc, int mask)
{
    int i = blockIdx.x * 256 + threadIdx.x;
    if (i < EE) {
        int r = et[i];
        int b = dst[i] * RR + r;
        int pos = atomicAdd(&cursors[b], 1);
        int2 p;
        p.x = src[i] * chc + (r & mask) * DL;
        p.y = __float_as_int(1.0f / (float)cnts[b]);
        epk[pos] = p;
    }
}

// ---------------- dense bf16 MFMA GEMM: frag-packed DOUBLE-buffered LDS (R14) ----
// Layer 2 + gate only (layer 1 is LUT-based). Frag-packed XOR-swizzled LDS,
// true double buffer (64KB), one barrier/K-tile, pinned prefetch,
// T1 bijective XCD remap. MODE 0: plain; 1: +bias; 2: +hacc+bias+sigmoid.
template<int K, int MODE>
__global__ __launch_bounds__(256) void dense_gemm(
    const ushort* __restrict__ A,    // [M][K] bf16
    const ushort* __restrict__ Bt,   // [NCOL][K] bf16 (rows = C cols)
    const float* __restrict__ bias,  // [NCOL] (MODE>=1)
    const ushort* __restrict__ haccp,// [M][256] bf16 (MODE==2)
    ushort* __restrict__ C,          // [M][NCOL] bf16
    int M, int NCOL)
{
    constexpr int NKT = K / 64;
    __shared__ __attribute__((aligned(16))) ushort Al[2][128 * 64];  // 2x16 KB
    __shared__ __attribute__((aligned(16))) ushort Bl[2][128 * 64];  // 2x16 KB

    // ---- T1: bijective XCD-chunked remap (m204) ----
    const int nwg  = gridDim.x * gridDim.y;
    const int flat = blockIdx.y * gridDim.x + blockIdx.x;
    const int q8 = nwg >> 3, r8 = nwg & 7;
    const int xcd = flat & 7, pos = flat >> 3;
    const int vid = ((xcd < r8) ? xcd * (q8 + 1) : r8 * (q8 + 1) + (xcd - r8) * q8) + pos;
    const int m0  = (vid / gridDim.x) * 128;
    const int n0  = (vid % gridDim.x) * 128;

    const int t    = threadIdx.x;
    const int lane = t & 63;
    const int wv   = t >> 6;
    const int wr   = (wv >> 1) * 64;  // wave row offset
    const int wc   = (wv & 1) * 64;   // wave col offset
    const int l15  = lane & 15;
    const int kg   = lane >> 4;

    // staging decomposition: thread covers rows sr+32i, global elems [sc, sc+8)
    const int sr = t >> 3;
    const int sc = (t & 7) * 8;
    const int g0 = sc,      g1 = sc + 4;
    const int s0 = ((g0 >> 5) << 2) + ((g0 & 15) >> 2), h0_ = (g0 >> 4) & 1;
    const int s1 = ((g1 >> 5) << 2) + ((g1 & 15) >> 2), h1_ = (g1 >> 4) & 1;

    int arow[4], brow[4];
    #pragma unroll
    for (int i = 0; i < 4; i++) {
        int r = sr + i * 32;
        arow[i] = min(m0 + r, M - 1);
        brow[i] = n0 + r;
    }

    uint4 av[4], bv[4];
    auto SLOAD = [&](int kt) {
        const ushort* Ak = A + kt * 64 + sc;
        const ushort* Bk = Bt + kt * 64 + sc;
        #pragma unroll
        for (int i = 0; i < 4; i++) av[i] = *(const uint4*)(Ak + (size_t)arow[i] * K);
        #pragma unroll
        for (int i = 0; i < 4; i++) bv[i] = *(const uint4*)(Bk + (size_t)brow[i] * K);
    };
    auto SWRITE = [&](int buf) {
        #pragma unroll
        for (int i = 0; i < 4; i++) {
            int row = sr + i * 32;
            int rx  = row & 7;
            int o0  = row * 64 + (((s0 ^ rx) << 3) + h0_ * 4);
            int o1  = row * 64 + (((s1 ^ rx) << 3) + h1_ * 4);
            *(uint2*)&Al[buf][o0] = make_uint2(av[i].x, av[i].y);
            *(uint2*)&Al[buf][o1] = make_uint2(av[i].z, av[i].w);
            *(uint2*)&Bl[buf][o0] = make_uint2(bv[i].x, bv[i].y);
            *(uint2*)&Bl[buf][o1] = make_uint2(bv[i].z, bv[i].w);
        }
    };

    f32x4 acc[4][4];
    #pragma unroll
    for (int mt = 0; mt < 4; mt++)
        #pragma unroll
        for (int nt = 0; nt < 4; nt++) acc[mt][nt] = (f32x4){0.f, 0.f, 0.f, 0.f};

    union FR { bf16x8 v; uint u[4]; };

    SLOAD(0);
    SWRITE(0);
    __syncthreads();

    for (int kt = 0; kt < NKT; kt++) {
        const int cur = kt & 1;
        if (kt + 1 < NKT) {
            SLOAD(kt + 1);                       // issue prefetch...
            __builtin_amdgcn_sched_barrier(0);   // ...pinned before the MFMA phase
        }
        const ushort* Ap = Al[cur];
        const ushort* Bp = Bl[cur];
        #pragma unroll
        for (int kb = 0; kb < 2; kb++) {
            const int s = kb * 4 + kg;
            FR a[4], b[4];
            #pragma unroll
            for (int mt = 0; mt < 4; mt++) {
                int row = wr + mt * 16 + l15;
                uint4 va = *(const uint4*)&Ap[row * 64 + ((s ^ (row & 7)) << 3)];
                a[mt].u[0] = va.x; a[mt].u[1] = va.y; a[mt].u[2] = va.z; a[mt].u[3] = va.w;
            }
            #pragma unroll
            for (int nt = 0; nt < 4; nt++) {
                int row = wc + nt * 16 + l15;
                uint4 vb = *(const uint4*)&Bp[row * 64 + ((s ^ (row & 7)) << 3)];
                b[nt].u[0] = vb.x; b[nt].u[1] = vb.y; b[nt].u[2] = vb.z; b[nt].u[3] = vb.w;
            }
            #pragma unroll
            for (int nt = 0; nt < 4; nt++)
                #pragma unroll
                for (int mt = 0; mt < 4; mt++)
                    acc[mt][nt] = __builtin_amdgcn_mfma_f32_16x16x32_bf16(a[mt].v, b[nt].v, acc[mt][nt], 0, 0, 0);
        }
        if (kt + 1 < NKT) {
            SWRITE(cur ^ 1);    // other buffer: safe vs concurrent readers of `cur`
            __syncthreads();    // new tile visible for next iteration
        }
    }

    // epilogue: C/D layout col=lane&15, row=(lane>>4)*4+i  (direct stores)
    #pragma unroll
    for (int nt = 0; nt < 4; nt++) {
        int col = n0 + wc + nt * 16 + l15;
        float bvv = (MODE >= 1) ? bias[col] : 0.f;
        #pragma unroll
        for (int mt = 0; mt < 4; mt++) {
            #pragma unroll
            for (int i = 0; i < 4; i++) {
                int row = m0 + wr + mt * 16 + kg * 4 + i;
                if (row < M) {
                    float v = acc[mt][nt][i] + bvv;
                    if (MODE == 2) {
                        v += bf2f(haccp[(size_t)row * DL + col]);
                        v = sigmoidf_(v);
                    }
                    C[(size_t)row * NCOL + col] = f2bf(v);
                }
            }
        }
    }
}

// ---------------- flat CSR gather-accumulate over relations [relStart, relEnd) ----
// epk packs (index, weight) per edge. Half-wave per node, 8 cols (16B) per
// lane; edges in 4-wide batches (clamped idx + zero weight).
__global__ __launch_bounds__(256) void gather_acc(
    const ushort* __restrict__ hrc,  // [N][chc] bf16
    const int2* __restrict__ epk,
    const int* __restrict__ offs,    // [N*8]
    ushort* __restrict__ hacc,       // [N][256] bf16
    int relStart, int relEnd, int first)
{
    int t = threadIdx.x;
    int slot = t >> 5;               // 0..7
    int l = t & 31;
    int n = blockIdx.x * 8 + slot;
    if (n >= NN) return;
    int e    = offs[n * 8 + relStart];
    int endE = (relEnd == 8 && n == NN - 1) ? EE : offs[n * 8 + relEnd];
    int c = l * 8;

    float acc[8];
    if (first) {
        #pragma unroll
        for (int q = 0; q < 8; q++) acc[q] = 0.f;
    } else {
        uint4 a = *(const uint4*)&hacc[(size_t)n * DL + c];
        unp8(acc, a);
    }

    for (; e < endE; e += 4) {
        int e1 = min(e + 1, endE - 1);
        int e2 = min(e + 2, endE - 1);
        int e3 = min(e + 3, endE - 1);
        int2 p0 = epk[e], p1 = epk[e1], p2 = epk[e2], p3 = epk[e3];
        float w0 = __int_as_float(p0.y);
        float w1 = (e + 1 < endE) ? __int_as_float(p1.y) : 0.f;
        float w2 = (e + 2 < endE) ? __int_as_float(p2.y) : 0.f;
        float w3 = (e + 3 < endE) ? __int_as_float(p3.y) : 0.f;
        uint4 v0 = *(const uint4*)&hrc[(size_t)p0.x + c];
        uint4 v1 = *(const uint4*)&hrc[(size_t)p1.x + c];
        uint4 v2 = *(const uint4*)&hrc[(size_t)p2.x + c];
        uint4 v3 = *(const uint4*)&hrc[(size_t)p3.x + c];
        accw8(acc, v0, w0); accw8(acc, v1, w1);
        accw8(acc, v2, w2); accw8(acc, v3, w3);
    }

    *(uint4*)&hacc[(size_t)n * DL + c] = pack8bf(acc);
}

// ---------------- BatchNorm stats over hg1 columns (vectorized) ----------------
__global__ __launch_bounds__(256) void bnstats_kernel(
    const ushort* __restrict__ hg1, float* __restrict__ colsum, float* __restrict__ colsum2)
{
    __shared__ float ss[8][256], ss2[8][256];
    int t = threadIdx.x;
    int g = t >> 5, l = t & 31;
    int c = l * 8;
    constexpr int RPB = (NN + 255) / 256;   // 196
    int row0 = blockIdx.x * RPB;
    int rend = min(row0 + RPB, NN);
    float s[8], s2[8];
    #pragma unroll
    for (int q = 0; q < 8; q++) { s[q] = 0.f; s2[q] = 0.f; }
    for (int r = row0 + g; r < rend; r += 8) {
        uint4 v = *(const uint4*)&hg1[(size_t)r * DL + c];
        float f[8]; unp8(f, v);
        #pragma unroll
        for (int q = 0; q < 8; q++) { s[q] += f[q]; s2[q] += f[q] * f[q]; }
    }
    #pragma unroll
    for (int q = 0; q < 8; q++) { ss[g][c + q] = s[q]; ss2[g][c + q] = s2[q]; }
    __syncthreads();
    float ts = 0.f, ts2 = 0.f;
    #pragma unroll
    for (int gg = 0; gg < 8; gg++) { ts += ss[gg][t]; ts2 += ss2[gg][t]; }
    atomicAdd(&colsum[t], ts);
    atomicAdd(&colsum2[t], ts2);
}

__global__ void bnfinal_kernel(
    const float* __restrict__ colsum, const float* __restrict__ colsum2,
    const float* __restrict__ gamma, float* __restrict__ mu, float* __restrict__ aa)
{
    int c = threadIdx.x;
    if (c < DL) {
        float m = colsum[c] / (float)NN;
        float var = colsum2[c] / (float)NN - m * m;
        mu[c] = m;
        aa[c] = rsqrtf(var + 1e-5f) * gamma[c];
    }
}

// ---------------- gate = relu(BN(hg1)) @ Wg2 + bg2 ; segment max ----------------
__global__ __launch_bounds__(256) void gate_kernel(
    const ushort* __restrict__ hg1, const float* __restrict__ mu,
    const float* __restrict__ aa, const float* __restrict__ beta,
    const float* __restrict__ Wg2, const float* __restrict__ bg2,
    const int* __restrict__ batch,
    float* __restrict__ gate, unsigned* __restrict__ gmaxu)
{
    int lane = threadIdx.x & 63;
    int wid = (blockIdx.x * blockDim.x + threadIdx.x) >> 6;
    int nw = (gridDim.x * blockDim.x) >> 6;
    int per = (NN + nw - 1) / nw;
    int n0 = wid * per;
    if (n0 >= NN) return;
    int n1 = min(n0 + per, NN);
    float bg2v = bg2[0];
    float lmax = -3.4e38f;
    int curb = batch[n0];
    for (int n = n0; n < n1; n++) {
        float s = 0.f;
        #pragma unroll
        for (int c = 0; c < 4; c++) {
            int d = c * 64 + lane;
            float v = bf2f(hg1[(size_t)n * DL + d]);
            float xn = (v - mu[d]) * aa[d] + beta[d];
            xn = fmaxf(xn, 0.f);
            s += xn * Wg2[d];
        }
        #pragma unroll
        for (int o = 32; o > 0; o >>= 1) s += __shfl_down(s, o, 64);
        if (lane == 0) {
            float g = s + bg2v;
            gate[n] = g;
            int b = batch[n];
            if (b != curb) {
                atomicMax(&gmaxu[curb], fenc(lmax));
                lmax = -3.4e38f; curb = b;
            }
            lmax = fmaxf(lmax, g);
        }
    }
    if (lane == 0) atomicMax(&gmaxu[curb], fenc(lmax));
}

// ---------------- exp + per-graph denom (contiguous 4-node runs/thread) ----
__global__ __launch_bounds__(256) void expdenom_kernel(
    const float* __restrict__ gate, const int* __restrict__ batch,
    const unsigned* __restrict__ gmaxu, float* __restrict__ ealpha, float* __restrict__ denom)
{
    int tid = blockIdx.x * 256 + threadIdx.x;
    int i0 = tid * 4;
    if (i0 >= NN) return;
    int i1 = min(i0 + 4, NN);
    int curb = batch[i0];
    float m = fdec(gmaxu[curb]);
    float lsum = 0.f;
    for (int i = i0; i < i1; i++) {
        int b = batch[i];
        if (b != curb) {
            atomicAdd(&denom[curb], lsum);
            lsum = 0.f; curb = b; m = fdec(gmaxu[b]);
        }
        float ex = expf(gate[i] - m);
        ealpha[i] = ex;
        lsum += ex;
    }
    atomicAdd(&denom[curb], lsum);
}

// ---------------- pooled[g] = sum (e/denom) * h2[n] (batch sorted, vectorized) ----
__global__ __launch_bounds__(256) void pool_kernel(
    const ushort* __restrict__ h2, const float* __restrict__ ealpha,
    const float* __restrict__ denom, const int* __restrict__ batch,
    float* __restrict__ pooled)
{
    int t = threadIdx.x;
    int g = t >> 5, l = t & 31;
    int c = l * 8;
    int row0 = blockIdx.x * 128 + g * 16;
    if (row0 >= NN) return;
    int rend = min(row0 + 16, NN);
    float acc[8];
    #pragma unroll
    for (int q = 0; q < 8; q++) acc[q] = 0.f;
    int curg = batch[row0];
    for (int r = row0; r < rend; r++) {
        int gb = batch[r];
        if (gb != curg) {
            float inv = 1.0f / denom[curg];
            #pragma unroll
            for (int q = 0; q < 8; q++) atomicAdd(&pooled[curg * DL + c + q], acc[q] * inv);
            #pragma unroll
            for (int q = 0; q < 8; q++) acc[q] = 0.f;
            curg = gb;
        }
        float w = ealpha[r];
        uint4 v = *(const uint4*)&h2[(size_t)r * DL + c];
        accw8(acc, v, w);
    }
    float inv = 1.0f / denom[curg];
    #pragma unroll
    for (int q = 0; q < 8; q++) atomicAdd(&pooled[curg * DL + c + q], acc[q] * inv);
}

__global__ void head_kernel(
    const float* __restrict__ pooled, const float* __restrict__ Wgl,
    const float* __restrict__ bgl, float* __restrict__ out)
{
    int g = blockIdx.x;
    int lane = threadIdx.x;           // 64
    float s = 0.f;
    #pragma unroll
    for (int c = 0; c < 4; c++) {
        int d = c * 64 + lane;
        s += pooled[g * DL + d] * Wgl[d];
    }
    #pragma unroll
    for (int o = 32; o > 0; o >>= 1) s += __shfl_down(s, o, 64);
    if (lane == 0) out[g] = sigmoidf_(s + bgl[0]);
}

extern "C" void kernel_launch(void* const* d_in, const int* in_sizes, int n_in,
                              void* d_out, int out_size, void* d_ws, size_t ws_size,
                              hipStream_t stream)
{
    const int* x      = (const int*)d_in[0];
    const int* ei     = (const int*)d_in[1];
    const int* etype  = (const int*)d_in[2];
    const int* batch  = (const int*)d_in[3];
    const float* e0   = (const float*)d_in[4];
    const float* e1   = (const float*)d_in[5];
    const float* e2   = (const float*)d_in[6];
    const float* e3   = (const float*)d_in[7];
    const float* e4   = (const float*)d_in[8];
    const float* e5   = (const float*)d_in[9];
    const float* W1   = (const float*)d_in[10];
    const float* root1= (const float*)d_in[11];
    const float* b1   = (const float*)d_in[12];
    const float* W2   = (const float*)d_in[13];
    const float* root2= (const float*)d_in[14];
    const float* b2   = (const float*)d_in[15];
    const float* Wg1  = (const float*)d_in[16];
    const float* bg1  = (const float*)d_in[17];
    const float* gamma= (const float*)d_in[18];
    const float* beta = (const float*)d_in[19];
    const float* Wg2  = (const float*)d_in[20];
    const float* bg2  = (const float*)d_in[21];
    const float* Wgl  = (const float*)d_in[22];
    const float* bgl  = (const float*)d_in[23];
    float* out = (float*)d_out;

    const int* esrc_in = ei;          // edge_index[0]
    const int* edst_in = ei + EE;     // edge_index[1]

    char* ws = (char*)d_ws;
    size_t off = 0;
    auto alloc = [&](size_t b) -> char* {
        char* p = ws + off;
        off += (b + 255) & ~(size_t)255;
        return p;
    };
    ushort* h2     = (ushort*)alloc((size_t)NN * DL * 2);    // 25.6 MB
    ushort* h1     = (ushort*)alloc((size_t)NN * DL * 2);    // 25.6 MB
    ushort* hacc   = (ushort*)alloc((size_t)NN * DL * 2);    // 25.6 MB bf16
    size_t zstart = off;                                     // ---- zeroed region ----
    int*      counts  = (int*)alloc((size_t)NN * RR * 4);
    float*    colsum  = (float*)alloc(DL * 4);
    float*    colsum2 = (float*)alloc(DL * 4);
    unsigned* gmaxu   = (unsigned*)alloc(GG * 4);
    float*    denom   = (float*)alloc(GG * 4);
    float*    pooled  = (float*)alloc((size_t)GG * DL * 4);
    size_t zbytes = off - zstart;                            // ---- end zeroed ----
    int*   offs    = (int*)alloc((size_t)NN * RR * 4);
    int*   cursors = (int*)alloc((size_t)NN * RR * 4);
    int2*  epk     = (int2*)alloc((size_t)EE * 8);           // packed (idx, weight)
    int*   blkSums = (int*)alloc(512);
    int*   blkOff  = (int*)alloc(512);
    float* mu      = (float*)alloc(DL * 4);
    float* aa      = (float*)alloc(DL * 4);
    float* gate    = (float*)alloc((size_t)NN * 4);
    float* ealpha  = (float*)alloc((size_t)NN * 4);
    ushort* Tlut   = (ushort*)alloc((size_t)NCR * 9 * DL * 2); // 230.4 KB LUT
    ushort* WbT2   = (ushort*)alloc((size_t)9 * DL * DL * 2);  // 1.18 MB
    ushort* WbTg   = (ushort*)alloc((size_t)1 * DL * DL * 2);  // 131 KB

    // hrc LAST (bf16): prefer 4-relation chunks (102.4 MB), else 2.
    int npc;
    ushort* hrc;
    {
        size_t need4 = ((size_t)NN * 4 * DL * 2 + 255) & ~(size_t)255;
        size_t need2 = ((size_t)NN * 2 * DL * 2 + 255) & ~(size_t)255;
        if (off + need4 <= ws_size)      { npc = 4; hrc = (ushort*)alloc((size_t)NN * 4 * DL * 2); }
        else if (off + need2 <= ws_size) { npc = 2; hrc = (ushort*)alloc((size_t)NN * 2 * DL * 2); }
        else return;   // fail loudly (wrong output) rather than corrupt
    }
    const int chc = npc * DL;

    ushort* hg1 = hrc;    // hrc dead after layer2's last gather

    hipMemsetAsync(ws + zstart, 0, zbytes, stream);

    // layer-1 LUT + layer-2/gate weight transposes
    lutbuild_kernel<<<NCR * 9, 256, 0, stream>>>(e0, e1, e2, e3, e4, e5, W1, root1, Tlut);
    count_kernel<<<(EE + 255) / 256, 256, 0, stream>>>(edst_in, etype, counts);
    {
        int tot2 = 9 * DL * DL;
        cvtT_kernel<<<(tot2 + 255) / 256, 256, 0, stream>>>(W2, root2, WbT2, RR, DL);
        int totg = 1 * DL * DL;
        cvtT_kernel<<<(totg + 255) / 256, 256, 0, stream>>>(nullptr, Wg1, WbTg, 0, DL);
    }

    const int M = NN * RR;
    const int NB = (M + SCAN_CHUNK - 1) / SCAN_CHUNK;   // 98
    scanA_kernel<<<NB, 256, 0, stream>>>(counts, M, blkSums);
    scanB_kernel<<<1, 64, 0, stream>>>(blkSums, NB, blkOff);
    scanC_kernel<<<NB, 256, 0, stream>>>(counts, M, blkOff, offs, cursors);
    scatter_kernel<<<(EE + 255) / 256, 256, 0, stream>>>(esrc_in, edst_in, etype, counts, cursors,
                                                          epk, chc, npc - 1);

    const int MT = (NN + 127) / 128;   // 391 M-tiles
    const dim3 GC(npc * 2, MT), G2(2, MT);
    const int ABLK = (NN + 7) / 8;

    // ---- layer 1 via LUT: per chunk, LUT-sum messages then gather ----
    for (int c0 = 0; c0 < RR; c0 += npc) {
        dim3 LG(512, npc, 2);
        lutsum_kernel<<<LG, 256, 0, stream>>>(Tlut, x, hrc, c0, chc);
        gather_acc<<<ABLK, 256, 0, stream>>>(hrc, epk, offs, hacc, c0, c0 + npc, c0 == 0);
    }
    lutfin_kernel<<<512, 256, 0, stream>>>(Tlut, x, hacc, b1, h1);

    // ---- layer 2 (IN=256), GEMM-based ----
    for (int c0 = 0; c0 < RR; c0 += npc) {
        dense_gemm<DL, 0><<<GC, 256, 0, stream>>>(h1, WbT2 + (size_t)c0 * DL * DL, nullptr, nullptr, hrc, NN, chc);
        gather_acc<<<ABLK, 256, 0, stream>>>(hrc, epk, offs, hacc, c0, c0 + npc, c0 == 0);
    }
    dense_gemm<DL, 2><<<G2, 256, 0, stream>>>(h1, WbT2 + (size_t)8 * DL * DL, b2, hacc, h2, NN, DL);

    // ---- gate linear (no act; BN follows) ----
    dense_gemm<DL, 1><<<G2, 256, 0, stream>>>(h2, WbTg, bg1, nullptr, hg1, NN, DL);

    bnstats_kernel<<<256, 256, 0, stream>>>(hg1, colsum, colsum2);
    bnfinal_kernel<<<1, 256, 0, stream>>>(colsum, colsum2, gamma, mu, aa);
    gate_kernel<<<512, 256, 0, stream>>>(hg1, mu, aa, beta, Wg2, bg2, batch, gate, gmaxu);
    expdenom_kernel<<<((NN + 3) / 4 + 255) / 256, 256, 0, stream>>>(gate, batch, gmaxu, ealpha, denom);
    pool_kernel<<<(NN + 127) / 128, 256, 0, stream>>>(h2, ealpha, denom, batch, pooled);
    head_kernel<<<GG, 64, 0, stream>>>(pooled, Wgl, bgl, out);
}

// Round 23
// 554.513 us; speedup vs baseline: 1.1514x; 1.1146x over previous
//
#include <hip/hip_runtime.h>
#include <hip/hip_bf16.h>
#include <cstdint>

#define NN 50000
#define EE 800000
#define RR 8
#define GG 128
#define D0 384
#define DL 256
#define NCR 50       // total embedding rows: 33+5+3+4+2+3
#define KL1 512      // layer-1 count-GEMM K (9*50 used + pad)

typedef __attribute__((ext_vector_type(8))) short bf16x8;
typedef __attribute__((ext_vector_type(8))) _Float16 f16x8;
typedef __attribute__((ext_vector_type(4))) float f32x4;

__device__ __forceinline__ float sigmoidf_(float x) { return 1.0f / (1.0f + expf(-x)); }

__device__ __forceinline__ ushort f2bf(float f) {
    uint u = __float_as_uint(f);
    u += 0x7fffu + ((u >> 16) & 1u);
    return (ushort)(u >> 16);
}
__device__ __forceinline__ uint pack2bf(float lo, float hi) {
    return (uint)f2bf(lo) | ((uint)f2bf(hi) << 16);
}
__device__ __forceinline__ float bf2f(ushort u) {
    return __uint_as_float((uint)u << 16);
}
// fp16 helpers (layer-1 count-GEMM path: 11-bit mantissa)
__device__ __forceinline__ ushort f2h(float f) {
    _Float16 h = (_Float16)f;
    return *(ushort*)&h;
}
__device__ __forceinline__ uint pack2h(float lo, float hi) {
    return (uint)f2h(lo) | ((uint)f2h(hi) << 16);
}

// acc[0..7] += w * bf16x8(v)
__device__ __forceinline__ void accw8(float* s, uint4 a, float w) {
    s[0] += w * __uint_as_float(a.x << 16);
    s[1] += w * __uint_as_float(a.x & 0xffff0000u);
    s[2] += w * __uint_as_float(a.y << 16);
    s[3] += w * __uint_as_float(a.y & 0xffff0000u);
    s[4] += w * __uint_as_float(a.z << 16);
    s[5] += w * __uint_as_float(a.z & 0xffff0000u);
    s[6] += w * __uint_as_float(a.w << 16);
    s[7] += w * __uint_as_float(a.w & 0xffff0000u);
}

// unpack 8 bf16 to fp32
__device__ __forceinline__ void unp8(float* f, uint4 a) {
    f[0] = __uint_as_float(a.x << 16);
    f[1] = __uint_as_float(a.x & 0xffff0000u);
    f[2] = __uint_as_float(a.y << 16);
    f[3] = __uint_as_float(a.y & 0xffff0000u);
    f[4] = __uint_as_float(a.z << 16);
    f[5] = __uint_as_float(a.z & 0xffff0000u);
    f[6] = __uint_as_float(a.w << 16);
    f[7] = __uint_as_float(a.w & 0xffff0000u);
}
__device__ __forceinline__ uint4 pack8bf(const float* f) {
    uint4 p;
    p.x = pack2bf(f[0], f[1]);
    p.y = pack2bf(f[2], f[3]);
    p.z = pack2bf(f[4], f[5]);
    p.w = pack2bf(f[6], f[7]);
    return p;
}

// order-preserving float->uint encoding for atomicMax
__device__ __forceinline__ unsigned fenc(float x) {
    unsigned u = __float_as_uint(x);
    return (u & 0x80000000u) ? ~u : (u | 0x80000000u);
}
__device__ __forceinline__ float fdec(unsigned u) {
    unsigned b = (u & 0x80000000u) ? (u & 0x7fffffffu) : ~u;
    return __uint_as_float(b);
}

// ---------------- layer-1 LUT build: T[cr][r][col] = emb_row(cr) @ W1[r, slice] ----
// Output fp16 (feeds the fp16 count-GEMM).
__global__ __launch_bounds__(256) void lutbuild_kernel(
    const float* __restrict__ e0, const float* __restrict__ e1,
    const float* __restrict__ e2, const float* __restrict__ e3,
    const float* __restrict__ e4, const float* __restrict__ e5,
    const float* __restrict__ W1, const float* __restrict__ root1,
    ushort* __restrict__ T)          // [50][9][256] fp16
{
    int b = blockIdx.x;              // 0..449
    int cr = b / 9;
    int r  = b - cr * 9;
    int t, c;
    if      (cr < 33) { t = 0; c = cr; }
    else if (cr < 38) { t = 1; c = cr - 33; }
    else if (cr < 41) { t = 2; c = cr - 38; }
    else if (cr < 45) { t = 3; c = cr - 41; }
    else if (cr < 47) { t = 4; c = cr - 45; }
    else              { t = 5; c = cr - 47; }
    const float* emb;
    switch (t) {
        case 0: emb = e0; break; case 1: emb = e1; break; case 2: emb = e2; break;
        case 3: emb = e3; break; case 4: emb = e4; break; default: emb = e5; break;
    }
    const float* er = emb + c * 64;
    int col = threadIdx.x;           // 256
    const float* Wb = (r < 8) ? (W1 + ((size_t)r * D0 + t * 64) * DL + col)
                              : (root1 + (size_t)(t * 64) * DL + col);
    float s = 0.f;
    #pragma unroll 8
    for (int k = 0; k < 64; k++) s += er[k] * Wb[(size_t)k * DL];
    T[(size_t)(cr * 9 + r) * DL + col] = f2h(s);
}

// ---------------- layer-1 GEMM B-operand: Bt[col][k] = T[k%50][k/50][col] ----------
// k = rr*50 + cr for rr in [0,9) (rr=8 is root); zeros in pad k in [450,512).
__global__ __launch_bounds__(256) void btl1_kernel(
    const ushort* __restrict__ T, ushort* __restrict__ Bt)   // [256][512] fp16
{
    int idx = blockIdx.x * 256 + threadIdx.x;
    if (idx >= 256 * KL1) return;
    int col = idx / KL1, k = idx - col * KL1;
    ushort v = 0;
    if (k < 450) {
        int rr = k / 50, cr = k - rr * 50;
        v = T[(size_t)(cr * 9 + rr) * 256 + col];
    }
    Bt[idx] = v;
}

// ---------------- layer-1 weight-histogram build (fp16 output) ----------------
// One thread per (node, slot); slot 0..7 = relation buckets, 8 = root.
// Accumulates edge weights into a 50-bin LDS row, packs to A[n][slot*50..+50).
__global__ __launch_bounds__(256) void cntbuild_kernel(
    const int* __restrict__ x,       // [N][6]
    const int2* __restrict__ epk,    // (src*8+r, weight), CSR-ordered
    const int* __restrict__ offs,    // [N*8]
    ushort* __restrict__ A)          // [N][512] fp16 (aliases hrc)
{
    __shared__ float Ls[256 * 53];   // 54.3 KB
    int t  = threadIdx.x;
    int id = blockIdx.x * 256 + t;
    int n  = id / 9;
    int rr = id - n * 9;
    if (n >= NN) return;
    float* row = &Ls[t * 53];
    #pragma unroll
    for (int j = 0; j < 50; j++) row[j] = 0.f;
    const int cumc[6] = {0, 33, 38, 41, 45, 47};

    if (rr < 8) {
        int b  = n * 8 + rr;
        int e0 = offs[b];
        int e1 = (b + 1 < NN * 8) ? offs[b + 1] : EE;
        for (int e = e0; e < e1; e++) {
            int2 p = epk[e];
            int s = p.x >> 3;
            float w = __int_as_float(p.y);
            const int* xp = x + s * 6;
            #pragma unroll
            for (int tb = 0; tb < 6; tb++) row[cumc[tb] + xp[tb]] += w;
        }
    } else {                          // root: exact one-hot counts of x[n]
        const int* xp = x + n * 6;
        #pragma unroll
        for (int tb = 0; tb < 6; tb++) row[cumc[tb] + xp[tb]] += 1.f;
    }

    ushort* dst = A + (size_t)n * KL1 + rr * 50;   // 4B-aligned (rr*100 bytes)
    #pragma unroll
    for (int j = 0; j < 50; j += 2)
        *(uint*)&dst[j] = pack2h(row[j], row[j + 1]);
    if (rr == 8) {                    // zero pad k in [450, 512)
        ushort* pz = A + (size_t)n * KL1 + 450;
        #pragma unroll
        for (int j = 0; j < 62; j += 2) *(uint*)&pz[j] = 0u;
    }
}

// ---------------- weight convert + transpose: WbT[r*256+n][k] = bf16(W[r][k][n]) ----------------
__global__ __launch_bounds__(256) void cvtT_kernel(
    const float* __restrict__ W, const float* __restrict__ root,
    ushort* __restrict__ WbT, int nrel, int IN)
{
    int idx = blockIdx.x * 256 + threadIdx.x;
    int tot = (nrel + 1) * DL * IN;
    if (idx >= tot) return;
    int k = idx % IN;
    int rn = idx / IN;
    int n = rn % DL;
    int r = rn / DL;
    float v = (r < nrel) ? W[((size_t)r * IN + k) * DL + n] : root[(size_t)k * DL + n];
    WbT[idx] = f2bf(v);
}

// ---------------- CSR build ----------------
__global__ __launch_bounds__(256) void count_kernel(
    const int* __restrict__ dst, const int* __restrict__ et, int* __restrict__ counts)
{
    int i = blockIdx.x * 256 + threadIdx.x;
    if (i < EE) atomicAdd(&counts[dst[i] * RR + et[i]], 1);
}

#define SCAN_CHUNK 4096
__global__ __launch_bounds__(256) void scanA_kernel(const int* __restrict__ cnt, int M, int* __restrict__ blkSums)
{
    __shared__ int s[256];
    int b = blockIdx.x, t = threadIdx.x;
    int base = b * SCAN_CHUNK + t * 16;
    int tot = 0;
    #pragma unroll
    for (int i = 0; i < 16; i++) { int idx = base + i; if (idx < M) tot += cnt[idx]; }
    s[t] = tot; __syncthreads();
    for (int off = 128; off > 0; off >>= 1) {
        if (t < off) s[t] += s[t + off];
        __syncthreads();
    }
    if (t == 0) blkSums[b] = s[0];
}

// wave-parallel exclusive scan over NB<=128 block sums
__global__ void scanB_kernel(const int* __restrict__ blkSums, int NB, int* __restrict__ blkOff)
{
    int l = threadIdx.x;              // 64 lanes
    int a = (l < NB) ? blkSums[l] : 0;
    int b = (64 + l < NB) ? blkSums[64 + l] : 0;
    int ia = a, ib = b;
    for (int o = 1; o < 64; o <<= 1) {
        int t0 = __shfl_up(ia, o, 64);
        if (l >= o) ia += t0;
        int t1 = __shfl_up(ib, o, 64);
        if (l >= o) ib += t1;
    }
    int tot0 = __shfl(ia, 63, 64);
    if (l < NB) blkOff[l] = ia - a;
    if (64 + l < NB) blkOff[64 + l] = tot0 + ib - b;
}

__global__ __launch_bounds__(256) void scanC_kernel(
    const int* __restrict__ cnt, int M, const int* __restrict__ blkOff,
    int* __restrict__ offs, int* __restrict__ curs)
{
    __shared__ int s[256];
    int b = blockIdx.x, t = threadIdx.x;
    int base = b * SCAN_CHUNK + t * 16;
    int loc[16];
    int tot = 0;
    #pragma unroll
    for (int i = 0; i < 16; i++) {
        int idx = base + i;
        int v = (idx < M) ? cnt[idx] : 0;
        loc[i] = tot; tot += v;
    }
    s[t] = tot; __syncthreads();
    for (int off = 1; off < 256; off <<= 1) {
        int v = (t >= off) ? s[t - off] : 0;
        __syncthreads();
        s[t] += v;
        __syncthreads();
    }
    int texc = s[t] - tot;           // exclusive prefix of this thread
    int bb = blkOff[b];
    #pragma unroll
    for (int i = 0; i < 16; i++) {
        int idx = base + i;
        if (idx < M) { int o = bb + texc + loc[i]; offs[idx] = o; curs[idx] = o; }
    }
}

// scatter: per-edge packed (src*8 + rel, weight) as int2 -> ONE 8B scattered
// store per edge. Decoded by cntbuild (layer 1) and gather_acc (layer 2).
__global__ __launch_bounds__(256) void scatter_kernel(
    const int* __restrict__ src, const int* __restrict__ dst, const int* __restrict__ et,
    const int* __restrict__ cnts, int* __restrict__ cursors,
    int2* __restrict__ epk)
{
    int i = blockIdx.x * 256 + threadIdx.x;
    if (i < EE) {
        int r = et[i];
        int b = dst[i] * RR + r;
        int pos = atomicAdd(&cursors[b], 1);
        int2 p;
        p.x = src[i] * 8 + r;
        p.y = __float_as_int(1.0f / (float)cnts[b]);
        epk[pos] = p;
    }
}

// ---------------- dense MFMA GEMM: frag-packed DOUBLE-buffered LDS (R14) ----
// DT 0: bf16 operands; DT 1: fp16 operands (layer-1 count GEMM).
// MODE 0: plain; 1: +bias; 2: +hacc(bf16)+bias+sigmoid; 3: +bias+sigmoid.
template<int K, int MODE, int DT>
__global__ __launch_bounds__(256) void dense_gemm(
    const ushort* __restrict__ A,    // [M][K]
    const ushort* __restrict__ Bt,   // [NCOL][K] (rows = C cols)
    const float* __restrict__ bias,  // [NCOL] (MODE>=1)
    const ushort* __restrict__ haccp,// [M][256] bf16 (MODE==2)
    ushort* __restrict__ C,          // [M][NCOL] bf16
    int M, int NCOL)
{
    constexpr int NKT = K / 64;
    __shared__ __attribute__((aligned(16))) ushort Al[2][128 * 64];  // 2x16 KB
    __shared__ __attribute__((aligned(16))) ushort Bl[2][128 * 64];  // 2x16 KB

    // ---- T1: bijective XCD-chunked remap (m204) ----
    const int nwg  = gridDim.x * gridDim.y;
    const int flat = blockIdx.y * gridDim.x + blockIdx.x;
    const int q8 = nwg >> 3, r8 = nwg & 7;
    const int xcd = flat & 7, pos = flat >> 3;
    const int vid = ((xcd < r8) ? xcd * (q8 + 1) : r8 * (q8 + 1) + (xcd - r8) * q8) + pos;
    const int m0  = (vid / gridDim.x) * 128;
    const int n0  = (vid % gridDim.x) * 128;

    const int t    = threadIdx.x;
    const int lane = t & 63;
    const int wv   = t >> 6;
    const int wr   = (wv >> 1) * 64;  // wave row offset
    const int wc   = (wv & 1) * 64;   // wave col offset
    const int l15  = lane & 15;
    const int kg   = lane >> 4;

    // staging decomposition: thread covers rows sr+32i, global elems [sc, sc+8)
    const int sr = t >> 3;
    const int sc = (t & 7) * 8;
    const int g0 = sc,      g1 = sc + 4;
    const int s0 = ((g0 >> 5) << 2) + ((g0 & 15) >> 2), h0_ = (g0 >> 4) & 1;
    const int s1 = ((g1 >> 5) << 2) + ((g1 & 15) >> 2), h1_ = (g1 >> 4) & 1;

    int arow[4], brow[4];
    #pragma unroll
    for (int i = 0; i < 4; i++) {
        int r = sr + i * 32;
        arow[i] = min(m0 + r, M - 1);
        brow[i] = n0 + r;
    }

    uint4 av[4], bv[4];
    auto SLOAD = [&](int kt) {
        const ushort* Ak = A + kt * 64 + sc;
        const ushort* Bk = Bt + kt * 64 + sc;
        #pragma unroll
        for (int i = 0; i < 4; i++) av[i] = *(const uint4*)(Ak + (size_t)arow[i] * K);
        #pragma unroll
        for (int i = 0; i < 4; i++) bv[i] = *(const uint4*)(Bk + (size_t)brow[i] * K);
    };
    auto SWRITE = [&](int buf) {
        #pragma unroll
        for (int i = 0; i < 4; i++) {
            int row = sr + i * 32;
            int rx  = row & 7;
            int o0  = row * 64 + (((s0 ^ rx) << 3) + h0_ * 4);
            int o1  = row * 64 + (((s1 ^ rx) << 3) + h1_ * 4);
            *(uint2*)&Al[buf][o0] = make_uint2(av[i].x, av[i].y);
            *(uint2*)&Al[buf][o1] = make_uint2(av[i].z, av[i].w);
            *(uint2*)&Bl[buf][o0] = make_uint2(bv[i].x, bv[i].y);
            *(uint2*)&Bl[buf][o1] = make_uint2(bv[i].z, bv[i].w);
        }
    };

    f32x4 acc[4][4];
    #pragma unroll
    for (int mt = 0; mt < 4; mt++)
        #pragma unroll
        for (int nt = 0; nt < 4; nt++) acc[mt][nt] = (f32x4){0.f, 0.f, 0.f, 0.f};

    union FR { bf16x8 v; f16x8 h; uint u[4]; };

    SLOAD(0);
    SWRITE(0);
    __syncthreads();

    for (int kt = 0; kt < NKT; kt++) {
        const int cur = kt & 1;
        if (kt + 1 < NKT) {
            SLOAD(kt + 1);                       // issue prefetch...
            __builtin_amdgcn_sched_barrier(0);   // ...pinned before the MFMA phase
        }
        const ushort* Ap = Al[cur];
        const ushort* Bp = Bl[cur];
        #pragma unroll
        for (int kb = 0; kb < 2; kb++) {
            const int s = kb * 4 + kg;
            FR a[4], b[4];
            #pragma unroll
            for (int mt = 0; mt < 4; mt++) {
                int row = wr + mt * 16 + l15;
                uint4 va = *(const uint4*)&Ap[row * 64 + ((s ^ (row & 7)) << 3)];
                a[mt].u[0] = va.x; a[mt].u[1] = va.y; a[mt].u[2] = va.z; a[mt].u[3] = va.w;
            }
            #pragma unroll
            for (int nt = 0; nt < 4; nt++) {
                int row = wc + nt * 16 + l15;
                uint4 vb = *(const uint4*)&Bp[row * 64 + ((s ^ (row & 7)) << 3)];
                b[nt].u[0] = vb.x; b[nt].u[1] = vb.y; b[nt].u[2] = vb.z; b[nt].u[3] = vb.w;
            }
            #pragma unroll
            for (int nt = 0; nt < 4; nt++)
                #pragma unroll
                for (int mt = 0; mt < 4; mt++) {
                    if (DT == 0)
                        acc[mt][nt] = __builtin_amdgcn_mfma_f32_16x16x32_bf16(a[mt].v, b[nt].v, acc[mt][nt], 0, 0, 0);
                    else
                        acc[mt][nt] = __builtin_amdgcn_mfma_f32_16x16x32_f16(a[mt].h, b[nt].h, acc[mt][nt], 0, 0, 0);
                }
        }
        if (kt + 1 < NKT) {
            SWRITE(cur ^ 1);    // other buffer: safe vs concurrent readers of `cur`
            __syncthreads();    // new tile visible for next iteration
        }
    }

    // epilogue: C/D layout col=lane&15, row=(lane>>4)*4+i  (direct stores)
    #pragma unroll
    for (int nt = 0; nt < 4; nt++) {
        int col = n0 + wc + nt * 16 + l15;
        float bvv = (MODE >= 1) ? bias[col] : 0.f;
        #pragma unroll
        for (int mt = 0; mt < 4; mt++) {
            #pragma unroll
            for (int i = 0; i < 4; i++) {
                int row = m0 + wr + mt * 16 + kg * 4 + i;
                if (row < M) {
                    float v = acc[mt][nt][i] + bvv;
                    if (MODE == 2) {
                        v += bf2f(haccp[(size_t)row * DL + col]);
                        v = sigmoidf_(v);
                    }
                    if (MODE == 3) v = sigmoidf_(v);
                    C[(size_t)row * NCOL + col] = f2bf(v);
                }
            }
        }
    }
}

// ---------------- flat CSR gather-accumulate over relations [relStart, relEnd) ----
// epk packs (src*8+rel, weight); hrc index decoded per edge. Half-wave per
// node, 8 cols (16B) per lane; edges in 4-wide batches.
__global__ __launch_bounds__(256) void gather_acc(
    const ushort* __restrict__ hrc,  // [N][chc] bf16
    const int2* __restrict__ epk,
    const int* __restrict__ offs,    // [N*8]
    ushort* __restrict__ hacc,       // [N][256] bf16
    int relStart, int relEnd, int first, int chc, int mask)
{
    int t = threadIdx.x;
    int slot = t >> 5;               // 0..7
    int l = t & 31;
    int n = blockIdx.x * 8 + slot;
    if (n >= NN) return;
    int e    = offs[n * 8 + relStart];
    int endE = (relEnd == 8 && n == NN - 1) ? EE : offs[n * 8 + relEnd];
    int c = l * 8;

    float acc[8];
    if (first) {
        #pragma unroll
        for (int q = 0; q < 8; q++) acc[q] = 0.f;
    } else {
        uint4 a = *(const uint4*)&hacc[(size_t)n * DL + c];
        unp8(acc, a);
    }

    for (; e < endE; e += 4) {
        int e1 = min(e + 1, endE - 1);
        int e2 = min(e + 2, endE - 1);
        int e3 = min(e + 3, endE - 1);
        int2 p0 = epk[e], p1 = epk[e1], p2 = epk[e2], p3 = epk[e3];
        float w0 = __int_as_float(p0.y);
        float w1 = (e + 1 < endE) ? __int_as_float(p1.y) : 0.f;
        float w2 = (e + 2 < endE) ? __int_as_float(p2.y) : 0.f;
        float w3 = (e + 3 < endE) ? __int_as_float(p3.y) : 0.f;
        int i0 = (p0.x >> 3) * chc + ((p0.x & 7) & mask) * DL;
        int i1 = (p1.x >> 3) * chc + ((p1.x & 7) & mask) * DL;
        int i2 = (p2.x >> 3) * chc + ((p2.x & 7) & mask) * DL;
        int i3 = (p3.x >> 3) * chc + ((p3.x & 7) & mask) * DL;
        uint4 v0 = *(const uint4*)&hrc[(size_t)i0 + c];
        uint4 v1 = *(const uint4*)&hrc[(size_t)i1 + c];
        uint4 v2 = *(const uint4*)&hrc[(size_t)i2 + c];
        uint4 v3 = *(const uint4*)&hrc[(size_t)i3 + c];
        accw8(acc, v0, w0); accw8(acc, v1, w1);
        accw8(acc, v2, w2); accw8(acc, v3, w3);
    }

    *(uint4*)&hacc[(size_t)n * DL + c] = pack8bf(acc);
}

// ---------------- BatchNorm stats over hg1 columns (vectorized) ----------------
__global__ __launch_bounds__(256) void bnstats_kernel(
    const ushort* __restrict__ hg1, float* __restrict__ colsum, float* __restrict__ colsum2)
{
    __shared__ float ss[8][256], ss2[8][256];
    int t = threadIdx.x;
    int g = t >> 5, l = t & 31;
    int c = l * 8;
    constexpr int RPB = (NN + 255) / 256;   // 196
    int row0 = blockIdx.x * RPB;
    int rend = min(row0 + RPB, NN);
    float s[8], s2[8];
    #pragma unroll
    for (int q = 0; q < 8; q++) { s[q] = 0.f; s2[q] = 0.f; }
    for (int r = row0 + g; r < rend; r += 8) {
        uint4 v = *(const uint4*)&hg1[(size_t)r * DL + c];
        float f[8]; unp8(f, v);
        #pragma unroll
        for (int q = 0; q < 8; q++) { s[q] += f[q]; s2[q] += f[q] * f[q]; }
    }
    #pragma unroll
    for (int q = 0; q < 8; q++) { ss[g][c + q] = s[q]; ss2[g][c + q] = s2[q]; }
    __syncthreads();
    float ts = 0.f, ts2 = 0.f;
    #pragma unroll
    for (int gg = 0; gg < 8; gg++) { ts += ss[gg][t]; ts2 += ss2[gg][t]; }
    atomicAdd(&colsum[t], ts);
    atomicAdd(&colsum2[t], ts2);
}

__global__ void bnfinal_kernel(
    const float* __restrict__ colsum, const float* __restrict__ colsum2,
    const float* __restrict__ gamma, float* __restrict__ mu, float* __restrict__ aa)
{
    int c = threadIdx.x;
    if (c < DL) {
        float m = colsum[c] / (float)NN;
        float var = colsum2[c] / (float)NN - m * m;
        mu[c] = m;
        aa[c] = rsqrtf(var + 1e-5f) * gamma[c];
    }
}

// ---------------- gate = relu(BN(hg1)) @ Wg2 + bg2 ; segment max ----------------
__global__ __launch_bounds__(256) void gate_kernel(
    const ushort* __restrict__ hg1, const float* __restrict__ mu,
    const float* __restrict__ aa, const float* __restrict__ beta,
    const float* __restrict__ Wg2, const float* __restrict__ bg2,
    const int* __restrict__ batch,
    float* __restrict__ gate, unsigned* __restrict__ gmaxu)
{
    int lane = threadIdx.x & 63;
    int wid = (blockIdx.x * blockDim.x + threadIdx.x) >> 6;
    int nw = (gridDim.x * blockDim.x) >> 6;
    int per = (NN + nw - 1) / nw;
    int n0 = wid * per;
    if (n0 >= NN) return;
    int n1 = min(n0 + per, NN);
    float bg2v = bg2[0];
    float lmax = -3.4e38f;
    int curb = batch[n0];
    for (int n = n0; n < n1; n++) {
        float s = 0.f;
        #pragma unroll
        for (int c = 0; c < 4; c++) {
            int d = c * 64 + lane;
            float v = bf2f(hg1[(size_t)n * DL + d]);
            float xn = (v - mu[d]) * aa[d] + beta[d];
            xn = fmaxf(xn, 0.f);
            s += xn * Wg2[d];
        }
        #pragma unroll
        for (int o = 32; o > 0; o >>= 1) s += __shfl_down(s, o, 64);
        if (lane == 0) {
            float g = s + bg2v;
            gate[n] = g;
            int b = batch[n];
            if (b != curb) {
                atomicMax(&gmaxu[curb], fenc(lmax));
                lmax = -3.4e38f; curb = b;
            }
            lmax = fmaxf(lmax, g);
        }
    }
    if (lane == 0) atomicMax(&gmaxu[curb], fenc(lmax));
}

// ---------------- exp + per-graph denom (contiguous 4-node runs/thread) ----
__global__ __launch_bounds__(256) void expdenom_kernel(
    const float* __restrict__ gate, const int* __restrict__ batch,
    const unsigned* __restrict__ gmaxu, float* __restrict__ ealpha, float* __restrict__ denom)
{
    int tid = blockIdx.x * 256 + threadIdx.x;
    int i0 = tid * 4;
    if (i0 >= NN) return;
    int i1 = min(i0 + 4, NN);
    int curb = batch[i0];
    float m = fdec(gmaxu[curb]);
    float lsum = 0.f;
    for (int i = i0; i < i1; i++) {
        int b = batch[i];
        if (b != curb) {
            atomicAdd(&denom[curb], lsum);
            lsum = 0.f; curb = b; m = fdec(gmaxu[b]);
        }
        float ex = expf(gate[i] - m);
        ealpha[i] = ex;
        lsum += ex;
    }
    atomicAdd(&denom[curb], lsum);
}

// ---------------- pooled[g] = sum (e/denom) * h2[n] (batch sorted, vectorized) ----
__global__ __launch_bounds__(256) void pool_kernel(
    const ushort* __restrict__ h2, const float* __restrict__ ealpha,
    const float* __restrict__ denom, const int* __restrict__ batch,
    float* __restrict__ pooled)
{
    int t = threadIdx.x;
    int g = t >> 5, l = t & 31;
    int c = l * 8;
    int row0 = blockIdx.x * 128 + g * 16;
    if (row0 >= NN) return;
    int rend = min(row0 + 16, NN);
    float acc[8];
    #pragma unroll
    for (int q = 0; q < 8; q++) acc[q] = 0.f;
    int curg = batch[row0];
    for (int r = row0; r < rend; r++) {
        int gb = batch[r];
        if (gb != curg) {
            float inv = 1.0f / denom[curg];
            #pragma unroll
            for (int q = 0; q < 8; q++) atomicAdd(&pooled[curg * DL + c + q], acc[q] * inv);
            #pragma unroll
            for (int q = 0; q < 8; q++) acc[q] = 0.f;
            curg = gb;
        }
        float w = ealpha[r];
        uint4 v = *(const uint4*)&h2[(size_t)r * DL + c];
        accw8(acc, v, w);
    }
    float inv = 1.0f / denom[curg];
    #pragma unroll
    for (int q = 0; q < 8; q++) atomicAdd(&pooled[curg * DL + c + q], acc[q] * inv);
}

__global__ void head_kernel(
    const float* __restrict__ pooled, const float* __restrict__ Wgl,
    const float* __restrict__ bgl, float* __restrict__ out)
{
    int g = blockIdx.x;
    int lane = threadIdx.x;           // 64
    float s = 0.f;
    #pragma unroll
    for (int c = 0; c < 4; c++) {
        int d = c * 64 + lane;
        s += pooled[g * DL + d] * Wgl[d];
    }
    #pragma unroll
    for (int o = 32; o > 0; o >>= 1) s += __shfl_down(s, o, 64);
    if (lane == 0) out[g] = sigmoidf_(s + bgl[0]);
}

extern "C" void kernel_launch(void* const* d_in, const int* in_sizes, int n_in,
                              void* d_out, int out_size, void* d_ws, size_t ws_size,
                              hipStream_t stream)
{
    const int* x      = (const int*)d_in[0];
    const int* ei     = (const int*)d_in[1];
    const int* etype  = (const int*)d_in[2];
    const int* batch  = (const int*)d_in[3];
    const float* e0   = (const float*)d_in[4];
    const float* e1   = (const float*)d_in[5];
    const float* e2   = (const float*)d_in[6];
    const float* e3   = (const float*)d_in[7];
    const float* e4   = (const float*)d_in[8];
    const float* e5   = (const float*)d_in[9];
    const float* W1   = (const float*)d_in[10];
    const float* root1= (const float*)d_in[11];
    const float* b1   = (const float*)d_in[12];
    const float* W2   = (const float*)d_in[13];
    const float* root2= (const float*)d_in[14];
    const float* b2   = (const float*)d_in[15];
    const float* Wg1  = (const float*)d_in[16];
    const float* bg1  = (const float*)d_in[17];
    const float* gamma= (const float*)d_in[18];
    const float* beta = (const float*)d_in[19];
    const float* Wg2  = (const float*)d_in[20];
    const float* bg2  = (const float*)d_in[21];
    const float* Wgl  = (const float*)d_in[22];
    const float* bgl  = (const float*)d_in[23];
    float* out = (float*)d_out;

    const int* esrc_in = ei;          // edge_index[0]
    const int* edst_in = ei + EE;     // edge_index[1]

    char* ws = (char*)d_ws;
    size_t off = 0;
    auto alloc = [&](size_t b) -> char* {
        char* p = ws + off;
        off += (b + 255) & ~(size_t)255;
        return p;
    };
    ushort* h2     = (ushort*)alloc((size_t)NN * DL * 2);    // 25.6 MB
    ushort* h1     = (ushort*)alloc((size_t)NN * DL * 2);    // 25.6 MB
    ushort* hacc   = (ushort*)alloc((size_t)NN * DL * 2);    // 25.6 MB bf16
    size_t zstart = off;                                     // ---- zeroed region ----
    int*      counts  = (int*)alloc((size_t)NN * RR * 4);
    float*    colsum  = (float*)alloc(DL * 4);
    float*    colsum2 = (float*)alloc(DL * 4);
    unsigned* gmaxu   = (unsigned*)alloc(GG * 4);
    float*    denom   = (float*)alloc(GG * 4);
    float*    pooled  = (float*)alloc((size_t)GG * DL * 4);
    size_t zbytes = off - zstart;                            // ---- end zeroed ----
    int*   offs    = (int*)alloc((size_t)NN * RR * 4);
    int*   cursors = (int*)alloc((size_t)NN * RR * 4);
    int2*  epk     = (int2*)alloc((size_t)EE * 8);           // packed (src*8+r, weight)
    int*   blkSums = (int*)alloc(512);
    int*   blkOff  = (int*)alloc(512);
    float* mu      = (float*)alloc(DL * 4);
    float* aa      = (float*)alloc(DL * 4);
    float* gate    = (float*)alloc((size_t)NN * 4);
    float* ealpha  = (float*)alloc((size_t)NN * 4);
    ushort* Tlut   = (ushort*)alloc((size_t)NCR * 9 * DL * 2); // 230.4 KB LUT (fp16)
    ushort* BtL1   = (ushort*)alloc((size_t)DL * KL1 * 2);     // 256 KB layer-1 B (fp16)
    ushort* WbT2   = (ushort*)alloc((size_t)9 * DL * DL * 2);  // 1.18 MB
    ushort* WbTg   = (ushort*)alloc((size_t)1 * DL * DL * 2);  // 131 KB

    // hrc LAST (bf16): prefer 4-relation chunks (102.4 MB), else 2.
    // cnt50 (layer-1 count matrix, N*512 fp16 = 51.2 MB) ALIASES hrc:
    // cnt50 dies after the layer-1 GEMM, hrc written afterwards by layer 2.
    int npc;
    ushort* hrc;
    {
        size_t need4 = ((size_t)NN * 4 * DL * 2 + 255) & ~(size_t)255;
        size_t need2 = ((size_t)NN * 2 * DL * 2 + 255) & ~(size_t)255;
        if (off + need4 <= ws_size)      { npc = 4; hrc = (ushort*)alloc((size_t)NN * 4 * DL * 2); }
        else if (off + need2 <= ws_size) { npc = 2; hrc = (ushort*)alloc((size_t)NN * 2 * DL * 2); }
        else return;   // fail loudly (wrong output) rather than corrupt
    }
    const int chc = npc * DL;
    ushort* cnt50 = hrc;   // [N][512] fp16, layer-1 only
    ushort* hg1   = hrc;   // hrc dead after layer2's last gather

    hipMemsetAsync(ws + zstart, 0, zbytes, stream);

    // layer-1 LUT + B-operand + layer-2/gate weight transposes
    lutbuild_kernel<<<NCR * 9, 256, 0, stream>>>(e0, e1, e2, e3, e4, e5, W1, root1, Tlut);
    btl1_kernel<<<(256 * KL1 + 255) / 256, 256, 0, stream>>>(Tlut, BtL1);
    count_kernel<<<(EE + 255) / 256, 256, 0, stream>>>(edst_in, etype, counts);
    {
        int tot2 = 9 * DL * DL;
        cvtT_kernel<<<(tot2 + 255) / 256, 256, 0, stream>>>(W2, root2, WbT2, RR, DL);
        int totg = 1 * DL * DL;
        cvtT_kernel<<<(totg + 255) / 256, 256, 0, stream>>>(nullptr, Wg1, WbTg, 0, DL);
    }

    const int M = NN * RR;
    const int NB = (M + SCAN_CHUNK - 1) / SCAN_CHUNK;   // 98
    scanA_kernel<<<NB, 256, 0, stream>>>(counts, M, blkSums);
    scanB_kernel<<<1, 64, 0, stream>>>(blkSums, NB, blkOff);
    scanC_kernel<<<NB, 256, 0, stream>>>(counts, M, blkOff, offs, cursors);
    scatter_kernel<<<(EE + 255) / 256, 256, 0, stream>>>(esrc_in, edst_in, etype, counts, cursors, epk);

    const int MT = (NN + 127) / 128;   // 391 M-tiles
    const dim3 GC(npc * 2, MT), G2(2, MT);   // NCOL/128 tiles in x (R22's bug: npc)
    const int ABLK = (NN + 7) / 8;

    // ---- layer 1: weight-histogram build + ONE K=512 fp16 GEMM -> h1 ----
    cntbuild_kernel<<<(NN * 9 + 255) / 256, 256, 0, stream>>>(x, epk, offs, cnt50);
    dense_gemm<KL1, 3, 1><<<G2, 256, 0, stream>>>(cnt50, BtL1, b1, nullptr, h1, NN, DL);

    // ---- layer 2 (IN=256), bf16 GEMM-based ----
    for (int c0 = 0; c0 < RR; c0 += npc) {
        dense_gemm<DL, 0, 0><<<GC, 256, 0, stream>>>(h1, WbT2 + (size_t)c0 * DL * DL, nullptr, nullptr, hrc, NN, chc);
        gather_acc<<<ABLK, 256, 0, stream>>>(hrc, epk, offs, hacc, c0, c0 + npc, c0 == 0, chc, npc - 1);
    }
    dense_gemm<DL, 2, 0><<<G2, 256, 0, stream>>>(h1, WbT2 + (size_t)8 * DL * DL, b2, hacc, h2, NN, DL);

    // ---- gate linear (no act; BN follows) ----
    dense_gemm<DL, 1, 0><<<G2, 256, 0, stream>>>(h2, WbTg, bg1, nullptr, hg1, NN, DL);

    bnstats_kernel<<<256, 256, 0, stream>>>(hg1, colsum, colsum2);
    bnfinal_kernel<<<1, 256, 0, stream>>>(colsum, colsum2, gamma, mu, aa);
    gate_kernel<<<512, 256, 0, stream>>>(hg1, mu, aa, beta, Wg2, bg2, batch, gate, gmaxu);
    expdenom_kernel<<<((NN + 3) / 4 + 255) / 256, 256, 0, stream>>>(gate, batch, gmaxu, ealpha, denom);
    pool_kernel<<<(NN + 127) / 128, 256, 0, stream>>>(h2, ealpha, denom, batch, pooled);
    head_kernel<<<GG, 64, 0, stream>>>(pooled, Wgl, bgl, out);
}